// Round 1
// baseline (553.662 us; speedup 1.0000x reference)
//
#include <hip/hip_runtime.h>

#define HW 16384      // 128*128
#define PR 130        // padded row stride
#define PS 16900      // padded plane 130*130

// ---------------- zero fill (padded buffers' borders must be 0) -------------
__global__ void zero_kernel(float* __restrict__ p, int n) {
    int stride = gridDim.x * blockDim.x;
    for (int i = blockIdx.x * blockDim.x + threadIdx.x; i < n; i += stride)
        p[i] = 0.f;
}

// ------------- bilinear up2x align_corners: x1(2,64,64,64) -> hp ch 64..127 --
__global__ void upsample_kernel(const float* __restrict__ x1, float* __restrict__ hp) {
    int idx = blockIdx.x * 256 + threadIdx.x;           // over 2*64*HW
    int hw = idx & (HW - 1);
    int bc = idx >> 14;                                  // b*64+c
    int c = bc & 63, b = bc >> 6;
    int oy = hw >> 7, ox = hw & 127;
    float fy = (float)(oy * 63) / 127.0f;
    float fx = (float)(ox * 63) / 127.0f;
    int y0 = (int)fy, x0 = (int)fx;
    float wy = fy - (float)y0, wx = fx - (float)x0;
    int y1 = min(y0 + 1, 63), x1i = min(x0 + 1, 63);
    const float* src = x1 + (bc << 12);                  // 64*64 plane
    float v00 = src[(y0 << 6) + x0], v01 = src[(y0 << 6) + x1i];
    float v10 = src[(y1 << 6) + x0], v11 = src[(y1 << 6) + x1i];
    float top = v00 * (1.f - wx) + v01 * wx;
    float bot = v10 * (1.f - wx) + v11 * wx;
    float v = top * (1.f - wy) + bot * wy;
    hp[(size_t)(b * 128 + 64 + c) * PS + (size_t)(oy + 1) * PR + (ox + 1)] = v;
}

// ------------- depthwise 3x3 + relu: hp ch 64..127 -> Qb[b][c][hw] ----------
__global__ void qconv_kernel(const float* __restrict__ hp, const float* __restrict__ Wq,
                             const float* __restrict__ bq, float* __restrict__ Qb) {
    int idx = blockIdx.x * 256 + threadIdx.x;            // over 2*64*HW
    int hw = idx & (HW - 1);
    int bc = idx >> 14;
    int c = bc & 63, b = bc >> 6;
    int y = hw >> 7, x = hw & 127;
    const float* s = hp + (size_t)(b * 128 + 64 + c) * PS + (size_t)(y + 1) * PR + (x + 1);
    const float* w = Wq + c * 9;
    float acc = bq[c];
    acc = fmaf(s[-PR - 1], w[0], acc);
    acc = fmaf(s[-PR],     w[1], acc);
    acc = fmaf(s[-PR + 1], w[2], acc);
    acc = fmaf(s[-1],      w[3], acc);
    acc = fmaf(s[0],       w[4], acc);
    acc = fmaf(s[1],       w[5], acc);
    acc = fmaf(s[PR - 1],  w[6], acc);
    acc = fmaf(s[PR],      w[7], acc);
    acc = fmaf(s[PR + 1],  w[8], acc);
    Qb[idx] = fmaxf(acc, 0.f);
}

// ------------- dense conv 3x3, 64->16, + relu: hp ch 64..127 -> Kf ----------
// grid (16, 32): blockIdx.y = b*16+k; each thread computes 4 adjacent x.
__global__ __launch_bounds__(256) void kconv_kernel(const float* __restrict__ hp,
                                                    const float* __restrict__ Wk,
                                                    const float* __restrict__ bk,
                                                    float* __restrict__ Kf) {
    __shared__ float wsh[576];
    int bkid = blockIdx.y;
    int k = bkid & 15, b = bkid >> 4;
    for (int i = threadIdx.x; i < 576; i += 256) wsh[i] = Wk[k * 576 + i];
    __syncthreads();
    int px = blockIdx.x * 1024 + threadIdx.x * 4;
    int y = px >> 7, x0 = px & 127;
    const float* base = hp + (size_t)(b * 128 + 64) * PS + (size_t)(y + 1) * PR + (x0 + 1);
    float a0 = bk[k], a1 = a0, a2 = a0, a3 = a0;
    for (int c = 0; c < 64; c++) {
        const float* s = base + (size_t)c * PS;
        const float* w = wsh + c * 9;
        #pragma unroll
        for (int r = 0; r < 3; r++) {
            const float* row = s + (r - 1) * PR;
            float v0 = row[-1], v1 = row[0], v2 = row[1], v3 = row[2], v4 = row[3], v5 = row[4];
            float w0 = w[r * 3 + 0], w1 = w[r * 3 + 1], w2 = w[r * 3 + 2];
            a0 = fmaf(v0, w0, fmaf(v1, w1, fmaf(v2, w2, a0)));
            a1 = fmaf(v1, w0, fmaf(v2, w1, fmaf(v3, w2, a1)));
            a2 = fmaf(v2, w0, fmaf(v3, w1, fmaf(v4, w2, a2)));
            a3 = fmaf(v3, w0, fmaf(v4, w1, fmaf(v5, w2, a3)));
        }
    }
    float4 r;
    r.x = fmaxf(a0, 0.f); r.y = fmaxf(a1, 0.f); r.z = fmaxf(a2, 0.f); r.w = fmaxf(a3, 0.f);
    *reinterpret_cast<float4*>(&Kf[((size_t)bkid << 14) + px]) = r;
}

// ------------- attention gate -> hp ch 0..63 --------------------------------
__global__ void gate_kernel(const float* __restrict__ Qb, const float* __restrict__ Kf,
                            const float* __restrict__ x2, const float* __restrict__ Wv,
                            const float* __restrict__ bv, float* __restrict__ hp) {
    int idx = blockIdx.x * 256 + threadIdx.x;            // over 2*64*HW
    int hw = idx & (HW - 1);
    int bc = idx >> 14;
    int c = bc & 63, b = bc >> 6;
    float q = Qb[idx];
    float xv = x2[idx];
    float s[16];
    float mx = -1e30f;
    #pragma unroll
    for (int k = 0; k < 16; k++) {
        float kf = Kf[((size_t)(b * 16 + k) << 14) + hw];
        s[k] = q * kf;
        mx = fmaxf(mx, s[k]);
    }
    float den = 0.f, num = 0.f;
    #pragma unroll
    for (int k = 0; k < 16; k++) {
        float e = __expf(s[k] - mx);
        den += e;
        float V = fmaxf(fmaf(xv, Wv[k], bv[k]), 0.f);
        num = fmaf(e, V, num);
    }
    int y = hw >> 7, x = hw & 127;
    hp[(size_t)(b * 128 + c) * PS + (size_t)(y + 1) * PR + (x + 1)] = num / den;
}

// ------------- conv 3x3 128->64 (no bias): hp -> cout[b][o][hw] -------------
// grid (16, 128): blockIdx.y = b*64+o
__global__ __launch_bounds__(256) void conv1_kernel(const float* __restrict__ hp,
                                                    const float* __restrict__ W1,
                                                    float* __restrict__ cout) {
    __shared__ float wsh[1152];
    int boid = blockIdx.y;
    int o = boid & 63, b = boid >> 6;
    for (int i = threadIdx.x; i < 1152; i += 256) wsh[i] = W1[o * 1152 + i];
    __syncthreads();
    int px = blockIdx.x * 1024 + threadIdx.x * 4;
    int y = px >> 7, x0 = px & 127;
    const float* base = hp + (size_t)(b * 128) * PS + (size_t)(y + 1) * PR + (x0 + 1);
    float a0 = 0.f, a1 = 0.f, a2 = 0.f, a3 = 0.f;
    for (int c = 0; c < 128; c++) {
        const float* s = base + (size_t)c * PS;
        const float* w = wsh + c * 9;
        #pragma unroll
        for (int r = 0; r < 3; r++) {
            const float* row = s + (r - 1) * PR;
            float v0 = row[-1], v1 = row[0], v2 = row[1], v3 = row[2], v4 = row[3], v5 = row[4];
            float w0 = w[r * 3 + 0], w1 = w[r * 3 + 1], w2 = w[r * 3 + 2];
            a0 = fmaf(v0, w0, fmaf(v1, w1, fmaf(v2, w2, a0)));
            a1 = fmaf(v1, w0, fmaf(v2, w1, fmaf(v3, w2, a1)));
            a2 = fmaf(v2, w0, fmaf(v3, w1, fmaf(v4, w2, a2)));
            a3 = fmaf(v3, w0, fmaf(v4, w1, fmaf(v5, w2, a3)));
        }
    }
    float4 r; r.x = a0; r.y = a1; r.z = a2; r.w = a3;
    *reinterpret_cast<float4*>(&cout[((size_t)boid << 14) + px]) = r;
}

// ------------- conv 3x3 64->64 (no bias): h1p -> cout ------------------------
__global__ __launch_bounds__(256) void conv2_kernel(const float* __restrict__ h1p,
                                                    const float* __restrict__ W2,
                                                    float* __restrict__ cout) {
    __shared__ float wsh[576];
    int boid = blockIdx.y;
    int o = boid & 63, b = boid >> 6;
    for (int i = threadIdx.x; i < 576; i += 256) wsh[i] = W2[o * 576 + i];
    __syncthreads();
    int px = blockIdx.x * 1024 + threadIdx.x * 4;
    int y = px >> 7, x0 = px & 127;
    const float* base = h1p + (size_t)(b * 64) * PS + (size_t)(y + 1) * PR + (x0 + 1);
    float a0 = 0.f, a1 = 0.f, a2 = 0.f, a3 = 0.f;
    for (int c = 0; c < 64; c++) {
        const float* s = base + (size_t)c * PS;
        const float* w = wsh + c * 9;
        #pragma unroll
        for (int r = 0; r < 3; r++) {
            const float* row = s + (r - 1) * PR;
            float v0 = row[-1], v1 = row[0], v2 = row[1], v3 = row[2], v4 = row[3], v5 = row[4];
            float w0 = w[r * 3 + 0], w1 = w[r * 3 + 1], w2 = w[r * 3 + 2];
            a0 = fmaf(v0, w0, fmaf(v1, w1, fmaf(v2, w2, a0)));
            a1 = fmaf(v1, w0, fmaf(v2, w1, fmaf(v3, w2, a1)));
            a2 = fmaf(v2, w0, fmaf(v3, w1, fmaf(v4, w2, a2)));
            a3 = fmaf(v3, w0, fmaf(v4, w1, fmaf(v5, w2, a3)));
        }
    }
    float4 r; r.x = a0; r.y = a1; r.z = a2; r.w = a3;
    *reinterpret_cast<float4*>(&cout[((size_t)boid << 14) + px]) = r;
}

// ------------- BN stats: one block per channel; stats = {scale[64],shift[64]}
__global__ void bnstats_kernel(const float* __restrict__ src, const float* __restrict__ g,
                               const float* __restrict__ beta, float* __restrict__ stats) {
    int ch = blockIdx.x;
    float s = 0.f, sq = 0.f;
    for (int b = 0; b < 2; b++) {
        const float* p = src + ((size_t)(b * 64 + ch) << 14);
        for (int i = threadIdx.x; i < HW; i += 256) {
            float v = p[i];
            s += v;
            sq = fmaf(v, v, sq);
        }
    }
    __shared__ float sh[512];
    sh[threadIdx.x] = s;
    sh[256 + threadIdx.x] = sq;
    __syncthreads();
    for (int off = 128; off > 0; off >>= 1) {
        if ((int)threadIdx.x < off) {
            sh[threadIdx.x] += sh[threadIdx.x + off];
            sh[256 + threadIdx.x] += sh[256 + threadIdx.x + off];
        }
        __syncthreads();
    }
    if (threadIdx.x == 0) {
        float mean = sh[0] * (1.f / 32768.f);
        float var = sh[256] * (1.f / 32768.f) - mean * mean;
        float scale = g[ch] * rsqrtf(var + 1e-5f);
        stats[ch] = scale;
        stats[64 + ch] = beta[ch] - mean * scale;
    }
}

// ------------- normalize+relu -> padded h1p ----------------------------------
__global__ void norm1_kernel(const float* __restrict__ src, const float* __restrict__ stats,
                             float* __restrict__ h1p) {
    int idx = blockIdx.x * 256 + threadIdx.x;            // over 2*64*HW
    int hw = idx & (HW - 1);
    int bc = idx >> 14;
    int c = bc & 63, b = bc >> 6;
    float v = fmaxf(fmaf(src[idx], stats[c], stats[64 + c]), 0.f);
    int y = hw >> 7, x = hw & 127;
    h1p[(size_t)(b * 64 + c) * PS + (size_t)(y + 1) * PR + (x + 1)] = v;
}

// ------------- normalize+relu, split o1/o2 -> d_out --------------------------
__global__ void norm2_kernel(const float* __restrict__ src, const float* __restrict__ stats,
                             float* __restrict__ out) {
    int idx = blockIdx.x * 256 + threadIdx.x;            // over 2*64*HW
    int hw = idx & (HW - 1);
    int bc = idx >> 14;
    int c = bc & 63, b = bc >> 6;
    float v = fmaxf(fmaf(src[idx], stats[c], stats[64 + c]), 0.f);
    int half = c >> 5, cc = c & 31;
    out[(size_t)half * 1048576 + (((size_t)(b * 32 + cc)) << 14) + hw] = v;
}

extern "C" void kernel_launch(void* const* d_in, const int* in_sizes, int n_in,
                              void* d_out, int out_size, void* d_ws, size_t ws_size,
                              hipStream_t stream) {
    const float* x1 = (const float*)d_in[0];
    // d_in[1] (x1_) is unused by the reference
    const float* x2 = (const float*)d_in[2];
    const float* Wq = (const float*)d_in[3];
    const float* bq = (const float*)d_in[4];
    const float* Wk = (const float*)d_in[5];
    const float* bk = (const float*)d_in[6];
    const float* Wv = (const float*)d_in[7];
    const float* bv = (const float*)d_in[8];
    const float* W1 = (const float*)d_in[9];
    const float* g1 = (const float*)d_in[10];
    const float* b1 = (const float*)d_in[11];
    const float* W2 = (const float*)d_in[12];
    const float* g2 = (const float*)d_in[13];
    const float* b2 = (const float*)d_in[14];
    float* out = (float*)d_out;
    float* ws = (float*)d_ws;

    // workspace layout (floats)
    float* hp    = ws;                 // [2][128][130][130] = 4,326,400
    float* h1p   = ws + 4326400;       // [2][64][130][130]  = 2,163,200
    float* Qb    = ws + 6489600;       // [2][64][128][128]  = 2,097,152
    float* Kf    = ws + 8586752;       // [2][16][128][128]  =   524,288
    float* cout_ = ws + 9111040;       // [2][64][128][128]  = 2,097,152
    float* stats = ws + 11208192;      // 256

    // zero padded buffers (hp + h1p are contiguous)
    zero_kernel<<<2048, 256, 0, stream>>>(hp, 6489600);
    upsample_kernel<<<8192, 256, 0, stream>>>(x1, hp);
    qconv_kernel<<<8192, 256, 0, stream>>>(hp, Wq, bq, Qb);
    kconv_kernel<<<dim3(16, 32), 256, 0, stream>>>(hp, Wk, bk, Kf);
    gate_kernel<<<8192, 256, 0, stream>>>(Qb, Kf, x2, Wv, bv, hp);
    conv1_kernel<<<dim3(16, 128), 256, 0, stream>>>(hp, W1, cout_);
    bnstats_kernel<<<64, 256, 0, stream>>>(cout_, g1, b1, stats);
    norm1_kernel<<<8192, 256, 0, stream>>>(cout_, stats, h1p);
    conv2_kernel<<<dim3(16, 128), 256, 0, stream>>>(h1p, W2, cout_);
    bnstats_kernel<<<64, 256, 0, stream>>>(cout_, g2, b2, stats + 128);
    norm2_kernel<<<8192, 256, 0, stream>>>(cout_, stats + 128, out);
}

// Round 2
// 234.521 us; speedup vs baseline: 2.3608x; 2.3608x over previous
//
#include <hip/hip_runtime.h>

#define HW 16384      // 128*128

// ---------------- transpose weights [O][C][3][3] -> [C][O][9] ----------------
__global__ void wtrans_kernel(const float* __restrict__ W, float* __restrict__ Wt,
                              int C, int O) {
    int i = blockIdx.x * 256 + threadIdx.x;
    int n = C * O * 9;
    if (i >= n) return;
    int t = i % 9;
    int co = i / 9;
    int o = co % O;
    int c = co / O;
    Wt[i] = W[((size_t)o * C + c) * 9 + t];
}

// ------------- bilinear up2x align_corners: x1(2,64,64,64) -> hcat ch 64..127
__global__ void upsample_kernel(const float* __restrict__ x1, float* __restrict__ hcat) {
    int idx = blockIdx.x * 256 + threadIdx.x;           // over 2*64*HW
    int hw = idx & (HW - 1);
    int bc = idx >> 14;                                  // b*64+c
    int c = bc & 63, b = bc >> 6;
    int oy = hw >> 7, ox = hw & 127;
    float fy = (float)(oy * 63) / 127.0f;
    float fx = (float)(ox * 63) / 127.0f;
    int y0 = (int)fy, x0 = (int)fx;
    float wy = fy - (float)y0, wx = fx - (float)x0;
    int y1 = min(y0 + 1, 63), x1i = min(x0 + 1, 63);
    const float* src = x1 + ((size_t)bc << 12);          // 64*64 plane
    float v00 = src[(y0 << 6) + x0], v01 = src[(y0 << 6) + x1i];
    float v10 = src[(y1 << 6) + x0], v11 = src[(y1 << 6) + x1i];
    float top = v00 * (1.f - wx) + v01 * wx;
    float bot = v10 * (1.f - wx) + v11 * wx;
    float v = top * (1.f - wy) + bot * wy;
    hcat[((size_t)(b * 128 + 64 + c) << 14) + hw] = v;
}

// ------------- fused qconv (depthwise 3x3+relu) + attention gate -> hcat ch 0..63
__global__ void gate_kernel(const float* __restrict__ hcat,   // reads ch 64..127, writes ch 0..63
                            const float* __restrict__ Kf,
                            const float* __restrict__ x2,
                            const float* __restrict__ Wq, const float* __restrict__ bq,
                            const float* __restrict__ Wv, const float* __restrict__ bv,
                            float* __restrict__ hout) {
    int idx = blockIdx.x * 256 + threadIdx.x;            // over 2*64*HW
    int hw = idx & (HW - 1);
    int bc = idx >> 14;
    int c = bc & 63, b = bc >> 6;
    int y = hw >> 7, x = hw & 127;

    // depthwise conv for Q at this pixel (zero 'SAME' padding)
    const float* up = hcat + ((size_t)(b * 128 + 64 + c) << 14);
    const float* wq = Wq + c * 9;                        // wave-uniform -> s_load
    float q = bq[c];
    #pragma unroll
    for (int dy = -1; dy <= 1; dy++) {
        #pragma unroll
        for (int dx = -1; dx <= 1; dx++) {
            int yy = y + dy, xx = x + dx;
            float v = ((unsigned)yy < 128u && (unsigned)xx < 128u) ? up[(yy << 7) + xx] : 0.f;
            q = fmaf(v, wq[(dy + 1) * 3 + (dx + 1)], q);
        }
    }
    q = fmaxf(q, 0.f);

    float xv = x2[idx];
    float s[16];
    float mx = -1e30f;
    #pragma unroll
    for (int k = 0; k < 16; k++) {
        float kf = Kf[((size_t)(b * 16 + k) << 14) + hw];
        s[k] = q * kf;
        mx = fmaxf(mx, s[k]);
    }
    float den = 0.f, num = 0.f;
    #pragma unroll
    for (int k = 0; k < 16; k++) {
        float e = __expf(s[k] - mx);
        den += e;
        float V = fmaxf(fmaf(xv, Wv[k], bv[k]), 0.f);
        num = fmaf(e, V, num);
    }
    hout[((size_t)(b * 128 + c) << 14) + hw] = num / den;
}

// ------------- generic LDS-tiled 3x3 conv, zero 'SAME' padding ---------------
// Block: 256 threads; tile = 4 rows x 128 cols; thread = 2 px x OCG out-channels.
// grid: (32, B * (COUT/OCG)).  Weights pre-transposed [c][o][9].
template<int CIN, int OCG, bool BIASRELU>
__global__ __launch_bounds__(256) void conv3x3_kernel(
    const float* __restrict__ src, int src_cpb, int src_coff,
    const float* __restrict__ Wt, int COUT,
    const float* __restrict__ bias,
    float* __restrict__ dst)
{
    __shared__ float tile[2][6 * 132];
    const int tid = threadIdx.x;
    const int tileY = blockIdx.x;                        // 0..31
    const int G = COUT / OCG;
    const int g = blockIdx.y % G, b = blockIdx.y / G;

    const float* sbase = src + ((size_t)(b * src_cpb + src_coff) << 14);
    const int r0 = tileY * 4 - 1;                        // global row of LDS row 0

    // precompute per-thread staging offsets (independent of channel)
    int soff[4];
    bool svalid[4];
    bool swrite[4];
    #pragma unroll
    for (int k = 0; k < 4; k++) {
        int i = tid + k * 256;
        swrite[k] = (k < 3) || (i < 792);
        int r = i / 132;
        int col = i - r * 132;
        int gr = r0 + r, gc = col - 1;
        svalid[k] = swrite[k] && (unsigned)gr < 128u && (unsigned)gc < 128u;
        soff[k] = (gr << 7) + gc;
    }

    const int row = tid >> 6;                            // 0..3
    const int col0 = (tid & 63) << 1;                    // 0,2,..126

    float acc[2][OCG];
    #pragma unroll
    for (int oc = 0; oc < OCG; oc++) {
        float b0 = BIASRELU ? bias[g * OCG + oc] : 0.f;
        acc[0][oc] = b0; acc[1][oc] = b0;
    }

    // stage channel 0
    {
        const float* plane = sbase;
        #pragma unroll
        for (int k = 0; k < 4; k++) {
            float v = svalid[k] ? plane[soff[k]] : 0.f;
            if (swrite[k]) tile[0][tid + k * 256] = v;
        }
    }
    __syncthreads();

    int buf = 0;
    for (int c = 0; c < CIN; c++) {
        // issue next channel's global loads early
        float sv[4];
        if (c + 1 < CIN) {
            const float* plane = sbase + ((size_t)(c + 1) << 14);
            #pragma unroll
            for (int k = 0; k < 4; k++)
                sv[k] = svalid[k] ? plane[soff[k]] : 0.f;
        }

        // weights for this channel (wave-uniform -> scalar loads)
        const float* wc = Wt + ((size_t)c * COUT + g * OCG) * 9;
        float w[OCG * 9];
        #pragma unroll
        for (int i = 0; i < OCG * 9; i++) w[i] = wc[i];

        // patch from LDS
        const float* tb = tile[buf];
        float p[3][4];
        #pragma unroll
        for (int r = 0; r < 3; r++) {
            const float* trow = tb + (row + r) * 132 + col0;
            float2 a  = *reinterpret_cast<const float2*>(trow);
            float2 b2 = *reinterpret_cast<const float2*>(trow + 2);
            p[r][0] = a.x; p[r][1] = a.y; p[r][2] = b2.x; p[r][3] = b2.y;
        }

        #pragma unroll
        for (int oc = 0; oc < OCG; oc++) {
            float a0 = acc[0][oc], a1 = acc[1][oc];
            #pragma unroll
            for (int r = 0; r < 3; r++) {
                float w0 = w[oc * 9 + r * 3 + 0];
                float w1 = w[oc * 9 + r * 3 + 1];
                float w2 = w[oc * 9 + r * 3 + 2];
                a0 = fmaf(p[r][0], w0, fmaf(p[r][1], w1, fmaf(p[r][2], w2, a0)));
                a1 = fmaf(p[r][1], w0, fmaf(p[r][2], w1, fmaf(p[r][3], w2, a1)));
            }
            acc[0][oc] = a0; acc[1][oc] = a1;
        }

        // write next channel into the other buffer
        if (c + 1 < CIN) {
            float* nb = tile[buf ^ 1];
            #pragma unroll
            for (int k = 0; k < 4; k++)
                if (swrite[k]) nb[tid + k * 256] = sv[k];
        }
        __syncthreads();
        buf ^= 1;
    }

    const int orow = tileY * 4 + row;
    #pragma unroll
    for (int oc = 0; oc < OCG; oc++) {
        float v0 = acc[0][oc], v1 = acc[1][oc];
        if (BIASRELU) { v0 = fmaxf(v0, 0.f); v1 = fmaxf(v1, 0.f); }
        float2 o; o.x = v0; o.y = v1;
        *reinterpret_cast<float2*>(
            &dst[(((size_t)(b * COUT + g * OCG + oc)) << 14) + (orow << 7) + col0]) = o;
    }
}

// ------------- BN stats: one block per channel; stats = {scale[64],shift[64]}
__global__ void bnstats_kernel(const float* __restrict__ src, const float* __restrict__ g,
                               const float* __restrict__ beta, float* __restrict__ stats) {
    int ch = blockIdx.x;
    float s = 0.f, sq = 0.f;
    for (int b = 0; b < 2; b++) {
        const float4* p = reinterpret_cast<const float4*>(src + ((size_t)(b * 64 + ch) << 14));
        for (int i = threadIdx.x; i < 4096; i += 256) {
            float4 v = p[i];
            s += v.x + v.y + v.z + v.w;
            sq = fmaf(v.x, v.x, fmaf(v.y, v.y, fmaf(v.z, v.z, fmaf(v.w, v.w, sq))));
        }
    }
    __shared__ float sh[512];
    sh[threadIdx.x] = s;
    sh[256 + threadIdx.x] = sq;
    __syncthreads();
    for (int off = 128; off > 0; off >>= 1) {
        if ((int)threadIdx.x < off) {
            sh[threadIdx.x] += sh[threadIdx.x + off];
            sh[256 + threadIdx.x] += sh[256 + threadIdx.x + off];
        }
        __syncthreads();
    }
    if (threadIdx.x == 0) {
        float mean = sh[0] * (1.f / 32768.f);
        float var = sh[256] * (1.f / 32768.f) - mean * mean;
        float scale = g[ch] * rsqrtf(var + 1e-5f);
        stats[ch] = scale;
        stats[64 + ch] = beta[ch] - mean * scale;
    }
}

// ------------- normalize+relu -> h1 (same layout), float4 --------------------
__global__ void norm1_kernel(const float4* __restrict__ src, const float* __restrict__ stats,
                             float4* __restrict__ dst) {
    int idx4 = blockIdx.x * 256 + threadIdx.x;           // over 2*64*4096
    int c = (idx4 >> 12) & 63;
    float sc = stats[c], sh = stats[64 + c];
    float4 v = src[idx4];
    v.x = fmaxf(fmaf(v.x, sc, sh), 0.f);
    v.y = fmaxf(fmaf(v.y, sc, sh), 0.f);
    v.z = fmaxf(fmaf(v.z, sc, sh), 0.f);
    v.w = fmaxf(fmaf(v.w, sc, sh), 0.f);
    dst[idx4] = v;
}

// ------------- normalize+relu, split o1/o2 -> d_out, float4 ------------------
__global__ void norm2_kernel(const float4* __restrict__ src, const float* __restrict__ stats,
                             float4* __restrict__ out) {
    int idx4 = blockIdx.x * 256 + threadIdx.x;           // over 2*64*4096
    int q = idx4 & 4095;
    int c = (idx4 >> 12) & 63;
    int b = idx4 >> 18;
    float sc = stats[c], sh = stats[64 + c];
    float4 v = src[idx4];
    v.x = fmaxf(fmaf(v.x, sc, sh), 0.f);
    v.y = fmaxf(fmaf(v.y, sc, sh), 0.f);
    v.z = fmaxf(fmaf(v.z, sc, sh), 0.f);
    v.w = fmaxf(fmaf(v.w, sc, sh), 0.f);
    int half = c >> 5, cc = c & 31;
    out[(size_t)half * 262144 + (((size_t)(b * 32 + cc)) << 12) + q] = v;
}

extern "C" void kernel_launch(void* const* d_in, const int* in_sizes, int n_in,
                              void* d_out, int out_size, void* d_ws, size_t ws_size,
                              hipStream_t stream) {
    const float* x1 = (const float*)d_in[0];
    // d_in[1] (x1_) is unused by the reference
    const float* x2 = (const float*)d_in[2];
    const float* Wq = (const float*)d_in[3];
    const float* bq = (const float*)d_in[4];
    const float* Wk = (const float*)d_in[5];
    const float* bk = (const float*)d_in[6];
    const float* Wv = (const float*)d_in[7];
    const float* bv = (const float*)d_in[8];
    const float* W1 = (const float*)d_in[9];
    const float* g1 = (const float*)d_in[10];
    const float* b1 = (const float*)d_in[11];
    const float* W2 = (const float*)d_in[12];
    const float* g2 = (const float*)d_in[13];
    const float* b2 = (const float*)d_in[14];
    float* out = (float*)d_out;
    float* ws = (float*)d_ws;

    // workspace layout (floats)
    float* hcat  = ws;                  // [2][128][HW]  gate ch0..63 | upsampled ch64..127
    float* Kf    = ws + 4194304;        // [2][16][HW]
    float* c1out = ws + 4718592;        // [2][64][HW]
    float* h1    = ws + 6815744;        // [2][64][HW]
    float* stats = ws + 8912896;        // 256
    float* Wt1   = ws + 8913152;        // 128*64*9
    float* Wt2   = ws + 8986880;        // 64*64*9
    float* Wtk   = ws + 9023744;        // 64*16*9

    wtrans_kernel<<<288, 256, 0, stream>>>(W1, Wt1, 128, 64);
    wtrans_kernel<<<144, 256, 0, stream>>>(W2, Wt2, 64, 64);
    wtrans_kernel<<<36,  256, 0, stream>>>(Wk, Wtk, 64, 16);

    upsample_kernel<<<8192, 256, 0, stream>>>(x1, hcat);

    // Kf = relu(conv 64->16) on upsampled channels
    conv3x3_kernel<64, 4, true><<<dim3(32, 2 * 4), 256, 0, stream>>>(
        hcat, 128, 64, Wtk, 16, bk, Kf);

    gate_kernel<<<8192, 256, 0, stream>>>(hcat, Kf, x2, Wq, bq, Wv, bv, hcat);

    // conv1: 128 -> 64
    conv3x3_kernel<128, 8, false><<<dim3(32, 2 * 8), 256, 0, stream>>>(
        hcat, 128, 0, Wt1, 64, nullptr, c1out);
    bnstats_kernel<<<64, 256, 0, stream>>>(c1out, g1, b1, stats);
    norm1_kernel<<<2048, 256, 0, stream>>>((const float4*)c1out, stats, (float4*)h1);

    // conv2: 64 -> 64
    conv3x3_kernel<64, 8, false><<<dim3(32, 2 * 8), 256, 0, stream>>>(
        h1, 64, 0, Wt2, 64, nullptr, c1out);
    bnstats_kernel<<<64, 256, 0, stream>>>(c1out, g2, b2, stats + 128);
    norm2_kernel<<<2048, 256, 0, stream>>>((const float4*)c1out, stats + 128, (float4*)out);
}

// Round 3
// 125.692 us; speedup vs baseline: 4.4049x; 1.8658x over previous
//
#include <hip/hip_runtime.h>

#define HW 16384      // 128*128

typedef __attribute__((ext_vector_type(8))) short short8v;
typedef __attribute__((ext_vector_type(4))) float f32x4;

__device__ inline short bf16rne(float x) {
    unsigned u = __float_as_uint(x);
    unsigned r = (u + 0x7fffu + ((u >> 16) & 1u)) >> 16;
    return (short)r;
}

// ---------------- weight prep: OIHW fp32 -> MFMA B-frag bf16 -----------------
// Wb[tap][chunk][octile][lane 64][j 8]; value = W[o][c][tap],
// o = octile*16 + (lane&15), c = chunk*32 + (lane>>4)*8 + j.
__global__ void wprep_kernel(const float* __restrict__ W, short* __restrict__ Wb,
                             int CIN, int COUT) {
    int idx = blockIdx.x * 256 + threadIdx.x;
    int NOCT = COUT >> 4, NCH = CIN >> 5;
    int total = 9 * NCH * NOCT * 512;
    if (idx >= total) return;
    int j = idx & 7, l = (idx >> 3) & 63;
    int rest = idx >> 9;
    int oct = rest % NOCT; rest /= NOCT;
    int ch = rest % NCH;
    int tap = rest / NCH;
    int o = oct * 16 + (l & 15);
    int c = ch * 32 + (l >> 4) * 8 + j;
    Wb[idx] = bf16rne(W[((size_t)o * CIN + c) * 9 + tap]);
}

// ------- upsample (bilinear 2x align-corners) + write fp32 NCHW + pack NHWC --
// block: (b, oy, xhalf); tile = 64 px x 64 ch.  hcatN ch 64..127 get 'up'.
__global__ __launch_bounds__(256) void upsample_pack_kernel(
    const float* __restrict__ x1, float* __restrict__ up, short* __restrict__ hcatN)
{
    __shared__ int lds[32 * 65];
    int bid = blockIdx.x;
    const int xh = bid & 1;
    const int oy = (bid >> 1) & 127;
    const int b = bid >> 8;
    const int t = threadIdx.x;
    {
        const int cw = t >> 3, pg = t & 7;
        float fy = (float)(oy * 63) / 127.f;
        int y0 = (int)fy; float wy = fy - (float)y0; int y1 = min(y0 + 1, 63);
        #pragma unroll
        for (int h = 0; h < 2; h++) {
            int c = cw * 2 + h;
            const float* sp = x1 + ((size_t)(b * 64 + c) << 12);
            float vals[8];
            #pragma unroll
            for (int i = 0; i < 8; i++) {
                int ox = xh * 64 + pg * 8 + i;
                float fx = (float)(ox * 63) / 127.f;
                int xx0 = (int)fx; float wx = fx - (float)xx0; int xx1 = min(xx0 + 1, 63);
                float v00 = sp[(y0 << 6) + xx0], v01 = sp[(y0 << 6) + xx1];
                float v10 = sp[(y1 << 6) + xx0], v11 = sp[(y1 << 6) + xx1];
                float top = v00 * (1.f - wx) + v01 * wx;
                float bot = v10 * (1.f - wx) + v11 * wx;
                vals[i] = top * (1.f - wy) + bot * wy;
            }
            float* dp = up + ((size_t)(b * 64 + c) << 14) + (oy << 7) + xh * 64 + pg * 8;
            #pragma unroll
            for (int i = 0; i < 8; i++) dp[i] = vals[i];
            #pragma unroll
            for (int i = 0; i < 8; i++) {
                unsigned wv = (unsigned)(unsigned short)bf16rne(vals[i]);
                if (h == 0) lds[cw * 65 + pg * 8 + i] = (int)wv;
                else        lds[cw * 65 + pg * 8 + i] |= (int)(wv << 16);
            }
        }
    }
    __syncthreads();
    {
        const int px = t >> 2, cq = t & 3;
        int wd[8];
        #pragma unroll
        for (int i = 0; i < 8; i++) wd[i] = lds[(cq * 8 + i) * 65 + px];
        int pixel = (oy << 7) + xh * 64 + px;
        int* dp = (int*)hcatN + (size_t)b * (HW * 64) + (size_t)pixel * 64 + 32 + cq * 8;
        *(int4*)dp = make_int4(wd[0], wd[1], wd[2], wd[3]);
        *(int4*)(dp + 4) = make_int4(wd[4], wd[5], wd[6], wd[7]);
    }
}

// ---------- NCHW fp32 (64ch) -> NHWC bf16, optional BN(scale,shift)+relu -----
template<bool NORM>
__global__ __launch_bounds__(256) void packN_kernel(
    const float* __restrict__ src, const float* __restrict__ stats,
    short* __restrict__ dstN, int PSW, int COFFW)
{
    __shared__ int lds[32 * 65];
    int bid = blockIdx.x;
    const int pxt = bid & 255;
    const int b = bid >> 8;
    const int t = threadIdx.x;
    {
        const int cw = t >> 3, pg = t & 7;
        #pragma unroll
        for (int h = 0; h < 2; h++) {
            int c = cw * 2 + h;
            const float* sp = src + ((size_t)(b * 64 + c) << 14) + pxt * 64 + pg * 8;
            float sc = 1.f, sh = 0.f;
            if (NORM) { sc = stats[c]; sh = stats[64 + c]; }
            float4 v0 = *(const float4*)sp;
            float4 v1 = *(const float4*)(sp + 4);
            float vals[8] = {v0.x, v0.y, v0.z, v0.w, v1.x, v1.y, v1.z, v1.w};
            #pragma unroll
            for (int i = 0; i < 8; i++) {
                if (NORM) vals[i] = fmaxf(fmaf(vals[i], sc, sh), 0.f);
                unsigned wv = (unsigned)(unsigned short)bf16rne(vals[i]);
                if (h == 0) lds[cw * 65 + pg * 8 + i] = (int)wv;
                else        lds[cw * 65 + pg * 8 + i] |= (int)(wv << 16);
            }
        }
    }
    __syncthreads();
    {
        const int px = t >> 2, cq = t & 3;
        int wd[8];
        #pragma unroll
        for (int i = 0; i < 8; i++) wd[i] = lds[(cq * 8 + i) * 65 + px];
        int pixel = pxt * 64 + px;
        int* dp = (int*)dstN + (size_t)b * HW * (size_t)PSW + (size_t)pixel * PSW + COFFW + cq * 8;
        *(int4*)dp = make_int4(wd[0], wd[1], wd[2], wd[3]);
        *(int4*)(dp + 4) = make_int4(wd[4], wd[5], wd[6], wd[7]);
    }
}

// ---------------- MFMA implicit-GEMM 3x3 conv, NHWC bf16 in, NCHW fp32 out ---
// wave = 16 px x (OPW*16) oc; block = 4 waves; NWN waves split N, NWM=4/NWN split M.
template<int PSTR, int COFF, int CIN, int COUT, int NWN, int OPW, bool BIASRELU>
__global__ __launch_bounds__(256) void convmfma_kernel(
    const short* __restrict__ actN, const short* __restrict__ Wb,
    const float* __restrict__ bias, float* __restrict__ dst)
{
    constexpr int NCH = CIN / 32, NOCT = COUT / 16, NWM = 4 / NWN;
    constexpr int SEG = 128 / (NWM * 16);
    const int t = threadIdx.x;
    const int w = t >> 6, l = t & 63;
    const int wn = w % NWN, wm = w / NWN;
    int bid = blockIdx.x;
    const int xseg = bid % SEG; bid /= SEG;
    const int y = bid & 127;
    const int b = bid >> 7;
    const int lx = l & 15, kg = l >> 4;
    const int x = xseg * (NWM * 16) + wm * 16 + lx;

    const short* abase = actN + (size_t)b * HW * PSTR + COFF + kg * 8;
    int pxo[3]; bool pxv[3];
    #pragma unroll
    for (int d = 0; d < 3; d++) {
        int xs = x + d - 1;
        pxv[d] = ((unsigned)xs < 128u);
        int xc = xs < 0 ? 0 : (xs > 127 ? 127 : xs);
        pxo[d] = xc * PSTR;
    }
    const short* wbase = Wb + (size_t)(wn * OPW) * 512 + (size_t)l * 8;

    f32x4 acc[OPW];
    #pragma unroll
    for (int p = 0; p < OPW; p++) acc[p] = (f32x4)(0.f);

    #pragma unroll
    for (int tap = 0; tap < 9; tap++) {
        const int dxi = tap % 3;
        const int ys = y + tap / 3 - 1;
        if ((unsigned)ys < 128u) {
            const short* arow = abase + (size_t)ys * 128 * PSTR;
            #pragma unroll
            for (int ch = 0; ch < NCH; ch++) {
                short8v a = *(const short8v*)(arow + pxo[dxi] + ch * 32);
                if (!pxv[dxi]) a = (short8v)(short)0;
                #pragma unroll
                for (int p = 0; p < OPW; p++) {
                    short8v bf = *(const short8v*)(wbase +
                        (size_t)((tap * NCH + ch) * NOCT + p) * 512);
                    acc[p] = __builtin_amdgcn_mfma_f32_16x16x32_bf16(a, bf, acc[p], 0, 0, 0);
                }
            }
        }
    }

    const int ox = xseg * (NWM * 16) + wm * 16 + kg * 4;
    #pragma unroll
    for (int p = 0; p < OPW; p++) {
        const int oc = (wn * OPW + p) * 16 + lx;
        f32x4 v = acc[p];
        if (BIASRELU) {
            float bb = bias[oc];
            #pragma unroll
            for (int r = 0; r < 4; r++) v[r] = fmaxf(v[r] + bb, 0.f);
        }
        *(f32x4*)(dst + (((size_t)(b * COUT + oc)) << 14) + (y << 7) + ox) = v;
    }
}

// ------------- fused qconv (depthwise 3x3+relu) + attention gate -------------
__global__ void gate_kernel(const float* __restrict__ up,
                            const float* __restrict__ Kf,
                            const float* __restrict__ x2,
                            const float* __restrict__ Wq, const float* __restrict__ bq,
                            const float* __restrict__ Wv, const float* __restrict__ bv,
                            float* __restrict__ gatebuf) {
    int idx = blockIdx.x * 256 + threadIdx.x;            // over 2*64*HW
    int hw = idx & (HW - 1);
    int bc = idx >> 14;
    int c = bc & 63, b = bc >> 6;
    int y = hw >> 7, x = hw & 127;

    const float* upc = up + ((size_t)(b * 64 + c) << 14);
    const float* wq = Wq + c * 9;                        // wave-uniform -> s_load
    float q = bq[c];
    #pragma unroll
    for (int dy = -1; dy <= 1; dy++) {
        #pragma unroll
        for (int dx = -1; dx <= 1; dx++) {
            int yy = y + dy, xx = x + dx;
            float v = ((unsigned)yy < 128u && (unsigned)xx < 128u) ? upc[(yy << 7) + xx] : 0.f;
            q = fmaf(v, wq[(dy + 1) * 3 + (dx + 1)], q);
        }
    }
    q = fmaxf(q, 0.f);

    float xv = x2[idx];
    float s[16];
    float mx = -1e30f;
    #pragma unroll
    for (int k = 0; k < 16; k++) {
        float kf = Kf[((size_t)(b * 16 + k) << 14) + hw];
        s[k] = q * kf;
        mx = fmaxf(mx, s[k]);
    }
    float den = 0.f, num = 0.f;
    #pragma unroll
    for (int k = 0; k < 16; k++) {
        float e = __expf(s[k] - mx);
        den += e;
        float V = fmaxf(fmaf(xv, Wv[k], bv[k]), 0.f);
        num = fmaf(e, V, num);
    }
    gatebuf[((size_t)(b * 64 + c) << 14) + hw] = num / den;
}

// ------------- BN stats: one block per channel; stats = {scale[64],shift[64]}
__global__ void bnstats_kernel(const float* __restrict__ src, const float* __restrict__ g,
                               const float* __restrict__ beta, float* __restrict__ stats) {
    int ch = blockIdx.x;
    float s = 0.f, sq = 0.f;
    for (int b = 0; b < 2; b++) {
        const float4* p = reinterpret_cast<const float4*>(src + ((size_t)(b * 64 + ch) << 14));
        for (int i = threadIdx.x; i < 4096; i += 256) {
            float4 v = p[i];
            s += v.x + v.y + v.z + v.w;
            sq = fmaf(v.x, v.x, fmaf(v.y, v.y, fmaf(v.z, v.z, fmaf(v.w, v.w, sq))));
        }
    }
    __shared__ float sh[512];
    sh[threadIdx.x] = s;
    sh[256 + threadIdx.x] = sq;
    __syncthreads();
    for (int off = 128; off > 0; off >>= 1) {
        if ((int)threadIdx.x < off) {
            sh[threadIdx.x] += sh[threadIdx.x + off];
            sh[256 + threadIdx.x] += sh[256 + threadIdx.x + off];
        }
        __syncthreads();
    }
    if (threadIdx.x == 0) {
        float mean = sh[0] * (1.f / 32768.f);
        float var = sh[256] * (1.f / 32768.f) - mean * mean;
        float scale = g[ch] * rsqrtf(var + 1e-5f);
        stats[ch] = scale;
        stats[64 + ch] = beta[ch] - mean * scale;
    }
}

// ------------- normalize+relu, split o1/o2 -> d_out, float4 ------------------
__global__ void norm2_kernel(const float4* __restrict__ src, const float* __restrict__ stats,
                             float4* __restrict__ out) {
    int idx4 = blockIdx.x * 256 + threadIdx.x;           // over 2*64*4096
    int q = idx4 & 4095;
    int c = (idx4 >> 12) & 63;
    int b = idx4 >> 18;
    float sc = stats[c], sh = stats[64 + c];
    float4 v = src[idx4];
    v.x = fmaxf(fmaf(v.x, sc, sh), 0.f);
    v.y = fmaxf(fmaf(v.y, sc, sh), 0.f);
    v.z = fmaxf(fmaf(v.z, sc, sh), 0.f);
    v.w = fmaxf(fmaf(v.w, sc, sh), 0.f);
    int half = c >> 5, cc = c & 31;
    out[(size_t)half * 262144 + (((size_t)(b * 32 + cc)) << 12) + q] = v;
}

extern "C" void kernel_launch(void* const* d_in, const int* in_sizes, int n_in,
                              void* d_out, int out_size, void* d_ws, size_t ws_size,
                              hipStream_t stream) {
    const float* x1 = (const float*)d_in[0];
    // d_in[1] (x1_) is unused by the reference
    const float* x2 = (const float*)d_in[2];
    const float* Wq = (const float*)d_in[3];
    const float* bq = (const float*)d_in[4];
    const float* Wk = (const float*)d_in[5];
    const float* bk = (const float*)d_in[6];
    const float* Wv = (const float*)d_in[7];
    const float* bv = (const float*)d_in[8];
    const float* W1 = (const float*)d_in[9];
    const float* g1 = (const float*)d_in[10];
    const float* b1 = (const float*)d_in[11];
    const float* W2 = (const float*)d_in[12];
    const float* g2 = (const float*)d_in[13];
    const float* b2 = (const float*)d_in[14];
    float* out = (float*)d_out;
    float* ws = (float*)d_ws;

    // workspace layout (float offsets)
    float* up     = ws;                       // [2][64][HW] fp32
    float* gatebuf= ws + 2097152;             // [2][64][HW] fp32
    float* Kf     = ws + 4194304;             // [2][16][HW] fp32
    float* c1out  = ws + 4718592;             // [2][64][HW] fp32
    float* stats  = ws + 6815744;             // 256
    short* hcatN  = (short*)(ws + 6816000);   // [2][HW][128] bf16
    short* h1N    = (short*)(ws + 8913152);   // [2][HW][64]  bf16
    short* Wb1    = (short*)(ws + 9961728);   // 9*4*4*512
    short* Wb2    = (short*)(ws + 9998592);   // 9*2*4*512
    short* Wbk    = (short*)(ws + 10017024);  // 9*2*1*512

    wprep_kernel<<<288, 256, 0, stream>>>(W1, Wb1, 128, 64);
    wprep_kernel<<<144, 256, 0, stream>>>(W2, Wb2, 64, 64);
    wprep_kernel<<<36,  256, 0, stream>>>(Wk, Wbk, 64, 16);

    upsample_pack_kernel<<<512, 256, 0, stream>>>(x1, up, hcatN);

    // Kf = relu(conv 64->16) on up channels (NHWC ch 64..127)
    convmfma_kernel<128, 64, 64, 16, 1, 1, true><<<512, 256, 0, stream>>>(
        hcatN, Wbk, bk, Kf);

    gate_kernel<<<8192, 256, 0, stream>>>(up, Kf, x2, Wq, bq, Wv, bv, gatebuf);
    packN_kernel<false><<<512, 256, 0, stream>>>(gatebuf, nullptr, hcatN, 64, 0);

    // conv1: 128 -> 64
    convmfma_kernel<128, 0, 128, 64, 2, 2, false><<<1024, 256, 0, stream>>>(
        hcatN, Wb1, nullptr, c1out);
    bnstats_kernel<<<64, 256, 0, stream>>>(c1out, g1, b1, stats);
    packN_kernel<true><<<512, 256, 0, stream>>>(c1out, stats, h1N, 32, 0);

    // conv2: 64 -> 64
    convmfma_kernel<64, 0, 64, 64, 2, 2, false><<<1024, 256, 0, stream>>>(
        h1N, Wb2, nullptr, c1out);
    bnstats_kernel<<<64, 256, 0, stream>>>(c1out, g2, b2, stats + 128);
    norm2_kernel<<<2048, 256, 0, stream>>>((const float4*)c1out, stats + 128, (float4*)out);
}

// Round 5
// 120.435 us; speedup vs baseline: 4.5972x; 1.0437x over previous
//
#include <hip/hip_runtime.h>

#define HW 16384      // 128*128

typedef __attribute__((ext_vector_type(8))) short short8v;
typedef __attribute__((ext_vector_type(4))) float f32x4;

__device__ inline short bf16rne(float x) {
    unsigned u = __float_as_uint(x);
    unsigned r = (u + 0x7fffu + ((u >> 16) & 1u)) >> 16;
    return (short)r;
}

// ---------------- fused weight prep: OIHW fp32 -> MFMA B-frag bf16 -----------
// Wb[tap][chunk][octile][lane 64][j 8]; value = W[o][c][tap],
// o = octile*16 + (lane&15), c = chunk*32 + (lane>>4)*8 + j.
__global__ void prep_kernel(const float* __restrict__ W1, const float* __restrict__ W2,
                            const float* __restrict__ Wk,
                            short* __restrict__ Wb1, short* __restrict__ Wb2,
                            short* __restrict__ Wbk) {
    int bid = blockIdx.x;
    const float* W; short* Wb; int CIN, COUT, idx;
    if (bid < 288)      { W = W1; Wb = Wb1; CIN = 128; COUT = 64; idx = bid * 256 + threadIdx.x; }
    else if (bid < 432) { W = W2; Wb = Wb2; CIN = 64;  COUT = 64; idx = (bid - 288) * 256 + threadIdx.x; }
    else                { W = Wk; Wb = Wbk; CIN = 64;  COUT = 16; idx = (bid - 432) * 256 + threadIdx.x; }
    int NOCT = COUT >> 4, NCH = CIN >> 5;
    int total = 9 * NCH * NOCT * 512;
    if (idx >= total) return;
    int j = idx & 7, l = (idx >> 3) & 63;
    int rest = idx >> 9;
    int oct = rest % NOCT; rest /= NOCT;
    int ch = rest % NCH;
    int tap = rest / NCH;
    int o = oct * 16 + (l & 15);
    int c = ch * 32 + (l >> 4) * 8 + j;
    Wb[idx] = bf16rne(W[((size_t)o * CIN + c) * 9 + tap]);
}

// ------- upsample (bilinear 2x align-corners) + write fp32 NCHW + pack NHWC --
__global__ __launch_bounds__(256) void upsample_pack_kernel(
    const float* __restrict__ x1, float* __restrict__ up, short* __restrict__ hcatN)
{
    __shared__ int lds[32 * 65];
    int bid = blockIdx.x;
    const int xh = bid & 1;
    const int oy = (bid >> 1) & 127;
    const int b = bid >> 8;
    const int t = threadIdx.x;
    {
        const int cw = t >> 3, pg = t & 7;
        float fy = (float)(oy * 63) / 127.f;
        int y0 = (int)fy; float wy = fy - (float)y0; int y1 = min(y0 + 1, 63);
        #pragma unroll
        for (int h = 0; h < 2; h++) {
            int c = cw * 2 + h;
            const float* sp = x1 + ((size_t)(b * 64 + c) << 12);
            float vals[8];
            #pragma unroll
            for (int i = 0; i < 8; i++) {
                int ox = xh * 64 + pg * 8 + i;
                float fx = (float)(ox * 63) / 127.f;
                int xx0 = (int)fx; float wx = fx - (float)xx0; int xx1 = min(xx0 + 1, 63);
                float v00 = sp[(y0 << 6) + xx0], v01 = sp[(y0 << 6) + xx1];
                float v10 = sp[(y1 << 6) + xx0], v11 = sp[(y1 << 6) + xx1];
                float top = v00 * (1.f - wx) + v01 * wx;
                float bot = v10 * (1.f - wx) + v11 * wx;
                vals[i] = top * (1.f - wy) + bot * wy;
            }
            float* dp = up + ((size_t)(b * 64 + c) << 14) + (oy << 7) + xh * 64 + pg * 8;
            #pragma unroll
            for (int i = 0; i < 8; i++) dp[i] = vals[i];
            #pragma unroll
            for (int i = 0; i < 8; i++) {
                unsigned wv = (unsigned)(unsigned short)bf16rne(vals[i]);
                if (h == 0) lds[cw * 65 + pg * 8 + i] = (int)wv;
                else        lds[cw * 65 + pg * 8 + i] |= (int)(wv << 16);
            }
        }
    }
    __syncthreads();
    {
        const int px = t >> 2, cq = t & 3;
        int wd[8];
        #pragma unroll
        for (int i = 0; i < 8; i++) wd[i] = lds[(cq * 8 + i) * 65 + px];
        int pixel = (oy << 7) + xh * 64 + px;
        int* dp = (int*)hcatN + (size_t)b * (HW * 64) + (size_t)pixel * 64 + 32 + cq * 8;
        *(int4*)dp = make_int4(wd[0], wd[1], wd[2], wd[3]);
        *(int4*)(dp + 4) = make_int4(wd[4], wd[5], wd[6], wd[7]);
    }
}

// ---------- NCHW fp32 (64ch) -> NHWC bf16 with BN(scale,shift)+relu ----------
__global__ __launch_bounds__(256) void packN_kernel(
    const float* __restrict__ src, const float* __restrict__ stats,
    short* __restrict__ dstN, int PSW)
{
    __shared__ int lds[32 * 65];
    int bid = blockIdx.x;
    const int pxt = bid & 255;
    const int b = bid >> 8;
    const int t = threadIdx.x;
    {
        const int cw = t >> 3, pg = t & 7;
        #pragma unroll
        for (int h = 0; h < 2; h++) {
            int c = cw * 2 + h;
            const float* sp = src + ((size_t)(b * 64 + c) << 14) + pxt * 64 + pg * 8;
            float sc = stats[c], sh = stats[64 + c];
            float4 v0 = *(const float4*)sp;
            float4 v1 = *(const float4*)(sp + 4);
            float vals[8] = {v0.x, v0.y, v0.z, v0.w, v1.x, v1.y, v1.z, v1.w};
            #pragma unroll
            for (int i = 0; i < 8; i++) {
                float v = fmaxf(fmaf(vals[i], sc, sh), 0.f);
                unsigned wv = (unsigned)(unsigned short)bf16rne(v);
                if (h == 0) lds[cw * 65 + pg * 8 + i] = (int)wv;
                else        lds[cw * 65 + pg * 8 + i] |= (int)(wv << 16);
            }
        }
    }
    __syncthreads();
    {
        const int px = t >> 2, cq = t & 3;
        int wd[8];
        #pragma unroll
        for (int i = 0; i < 8; i++) wd[i] = lds[(cq * 8 + i) * 65 + px];
        int pixel = pxt * 64 + px;
        int* dp = (int*)dstN + (size_t)b * HW * (size_t)PSW + (size_t)pixel * PSW + cq * 8;
        *(int4*)dp = make_int4(wd[0], wd[1], wd[2], wd[3]);
        *(int4*)(dp + 4) = make_int4(wd[4], wd[5], wd[6], wd[7]);
    }
}

// ---------------- MFMA implicit-GEMM 3x3 conv, NHWC bf16 in, NCHW fp32 out ---
// wave = (MB*16) px x (OPW*16) oc; block = 4 waves (NWN split oc, NWM=4/NWN split x).
template<int PSTR, int COFF, int CIN, int COUT, int NWN, int OPW, int MB, bool BIASRELU>
__global__ __launch_bounds__(256) void convmfma_kernel(
    const short* __restrict__ actN, const short* __restrict__ Wb,
    const float* __restrict__ bias, float* __restrict__ dst)
{
    constexpr int NCH = CIN / 32, NOCT = COUT / 16, NWM = 4 / NWN;
    constexpr int EXT = NWM * MB * 16;
    constexpr int SEG = 128 / EXT;
    const int t = threadIdx.x;
    const int w = t >> 6, l = t & 63;
    const int wn = w % NWN, wm = w / NWN;
    int bid = blockIdx.x;
    const int xseg = bid % SEG; bid /= SEG;
    const int y = bid & 127;
    const int b = bid >> 7;
    const int lx = l & 15, kg = l >> 4;

    const short* abase = actN + (size_t)b * HW * PSTR + COFF + kg * 8;
    int pxo[MB][3]; bool pxv[MB][3];
    #pragma unroll
    for (int m = 0; m < MB; m++) {
        int x = xseg * EXT + wm * (MB * 16) + m * 16 + lx;
        #pragma unroll
        for (int d = 0; d < 3; d++) {
            int xs = x + d - 1;
            pxv[m][d] = ((unsigned)xs < 128u);
            int xc = xs < 0 ? 0 : (xs > 127 ? 127 : xs);
            pxo[m][d] = xc * PSTR;
        }
    }
    const short* wbase = Wb + (size_t)(wn * OPW) * 512 + (size_t)l * 8;

    f32x4 acc[MB][OPW];
    #pragma unroll
    for (int m = 0; m < MB; m++)
        #pragma unroll
        for (int p = 0; p < OPW; p++) acc[m][p] = (f32x4)(0.f);

    #pragma unroll
    for (int tap = 0; tap < 9; tap++) {
        const int dxi = tap % 3;
        const int ys = y + tap / 3 - 1;
        if ((unsigned)ys < 128u) {
            const short* arow = abase + (size_t)ys * 128 * PSTR;
            #pragma unroll
            for (int ch = 0; ch < NCH; ch++) {
                short8v a[MB];
                #pragma unroll
                for (int m = 0; m < MB; m++) {
                    a[m] = *(const short8v*)(arow + pxo[m][dxi] + ch * 32);
                    if (!pxv[m][dxi]) a[m] = (short8v)(short)0;
                }
                #pragma unroll
                for (int p = 0; p < OPW; p++) {
                    short8v bf = *(const short8v*)(wbase +
                        (size_t)((tap * NCH + ch) * NOCT + p) * 512);
                    #pragma unroll
                    for (int m = 0; m < MB; m++)
                        acc[m][p] = __builtin_amdgcn_mfma_f32_16x16x32_bf16(a[m], bf, acc[m][p], 0, 0, 0);
                }
            }
        }
    }

    #pragma unroll
    for (int m = 0; m < MB; m++) {
        const int ox = xseg * EXT + wm * (MB * 16) + m * 16 + kg * 4;
        #pragma unroll
        for (int p = 0; p < OPW; p++) {
            const int oc = (wn * OPW + p) * 16 + lx;
            f32x4 v = acc[m][p];
            if (BIASRELU) {
                float bb = bias[oc];
                #pragma unroll
                for (int r = 0; r < 4; r++) v[r] = fmaxf(v[r] + bb, 0.f);
            }
            *(f32x4*)(dst + (((size_t)(b * COUT + oc)) << 14) + (y << 7) + ox) = v;
        }
    }
}

// ------------- fused qconv + softmax gate + NHWC bf16 pack -------------------
// block = (b, y, xh): 64 px x 64 gate channels -> hcatN ch 0..63
__global__ __launch_bounds__(256) void gate_kernel(
    const float* __restrict__ up, const float* __restrict__ Kf,
    const float* __restrict__ x2,
    const float* __restrict__ Wq, const float* __restrict__ bq,
    const float* __restrict__ Wv, const float* __restrict__ bv,
    short* __restrict__ hcatN)
{
    __shared__ float kfs[16 * 65];
    __shared__ int tr[32 * 65];
    int bid = blockIdx.x;
    const int xh = bid & 1;
    const int y = (bid >> 1) & 127;
    const int b = bid >> 8;
    const int t = threadIdx.x;

    {   // stage Kf tile [16 k][64 px]
        int i = t * 4;
        int k = i >> 6, px = i & 63;
        const float* sp = Kf + ((size_t)(b * 16 + k) << 14) + (y << 7) + xh * 64 + px;
        float4 v = *(const float4*)sp;
        float* d = kfs + k * 65 + px;
        d[0] = v.x; d[1] = v.y; d[2] = v.z; d[3] = v.w;
    }
    __syncthreads();

    const int cw = t >> 3, pg = t & 7;
    const int x0 = xh * 64 + pg * 8;

    float q8[2][8], xv[2][8];
    #pragma unroll
    for (int h = 0; h < 2; h++) {
        int c = cw * 2 + h;
        const float* upc = up + ((size_t)(b * 64 + c) << 14);
        float f[3][10];
        #pragma unroll
        for (int r = 0; r < 3; r++) {
            int yy = y + r - 1;
            bool yv = ((unsigned)yy < 128u);
            const float* rp = upc + (yy << 7);
            #pragma unroll
            for (int i = 0; i < 10; i++) {
                int xi = x0 - 1 + i;
                f[r][i] = (yv && (unsigned)xi < 128u) ? rp[xi] : 0.f;
            }
        }
        const float* wq = Wq + c * 9;
        float bqc = bq[c];
        #pragma unroll
        for (int i = 0; i < 8; i++) {
            float a = bqc;
            #pragma unroll
            for (int r = 0; r < 3; r++) {
                a = fmaf(f[r][i],     wq[r * 3 + 0], a);
                a = fmaf(f[r][i + 1], wq[r * 3 + 1], a);
                a = fmaf(f[r][i + 2], wq[r * 3 + 2], a);
            }
            q8[h][i] = fmaxf(a, 0.f);
        }
        const float* xp = x2 + ((size_t)(b * 64 + c) << 14) + (y << 7) + x0;
        float4 va = *(const float4*)xp;
        float4 vb = *(const float4*)(xp + 4);
        xv[h][0] = va.x; xv[h][1] = va.y; xv[h][2] = va.z; xv[h][3] = va.w;
        xv[h][4] = vb.x; xv[h][5] = vb.y; xv[h][6] = vb.z; xv[h][7] = vb.w;
    }

    float gv[2][8];
    #pragma unroll
    for (int i = 0; i < 8; i++) {
        int pl = pg * 8 + i;
        float kv[16];
        #pragma unroll
        for (int k = 0; k < 16; k++) kv[k] = kfs[k * 65 + pl];
        #pragma unroll
        for (int h = 0; h < 2; h++) {
            float q = q8[h][i];
            float mx = 0.f;                          // s_k = q*kv >= 0, so max >= 0
            #pragma unroll
            for (int k = 0; k < 16; k++) mx = fmaxf(mx, q * kv[k]);
            float den = 0.f, num = 0.f;
            float xvv = xv[h][i];
            #pragma unroll
            for (int k = 0; k < 16; k++) {
                float e = __expf(q * kv[k] - mx);
                den += e;
                float V = fmaxf(fmaf(xvv, Wv[k], bv[k]), 0.f);
                num = fmaf(e, V, num);
            }
            gv[h][i] = num / den;
        }
    }

    #pragma unroll
    for (int i = 0; i < 8; i++) {
        unsigned lo = (unsigned)(unsigned short)bf16rne(gv[0][i]);
        unsigned hi = (unsigned)(unsigned short)bf16rne(gv[1][i]);
        tr[cw * 65 + pg * 8 + i] = (int)(lo | (hi << 16));
    }
    __syncthreads();
    {
        const int px = t >> 2, cq = t & 3;
        int wd[8];
        #pragma unroll
        for (int i = 0; i < 8; i++) wd[i] = tr[(cq * 8 + i) * 65 + px];
        int pixel = (y << 7) + xh * 64 + px;
        int* dp = (int*)hcatN + (size_t)b * (HW * 64) + (size_t)pixel * 64 + cq * 8;
        *(int4*)dp = make_int4(wd[0], wd[1], wd[2], wd[3]);
        *(int4*)(dp + 4) = make_int4(wd[4], wd[5], wd[6], wd[7]);
    }
}

// ------------- BN stats: one block per channel; stats = {scale[64],shift[64]}
__global__ void bnstats_kernel(const float* __restrict__ src, const float* __restrict__ g,
                               const float* __restrict__ beta, float* __restrict__ stats) {
    int ch = blockIdx.x;
    float s = 0.f, sq = 0.f;
    for (int b = 0; b < 2; b++) {
        const float4* p = reinterpret_cast<const float4*>(src + ((size_t)(b * 64 + ch) << 14));
        for (int i = threadIdx.x; i < 4096; i += 256) {
            float4 v = p[i];
            s += v.x + v.y + v.z + v.w;
            sq = fmaf(v.x, v.x, fmaf(v.y, v.y, fmaf(v.z, v.z, fmaf(v.w, v.w, sq))));
        }
    }
    __shared__ float sh[512];
    sh[threadIdx.x] = s;
    sh[256 + threadIdx.x] = sq;
    __syncthreads();
    for (int off = 128; off > 0; off >>= 1) {
        if ((int)threadIdx.x < off) {
            sh[threadIdx.x] += sh[threadIdx.x + off];
            sh[256 + threadIdx.x] += sh[256 + threadIdx.x + off];
        }
        __syncthreads();
    }
    if (threadIdx.x == 0) {
        float mean = sh[0] * (1.f / 32768.f);
        float var = sh[256] * (1.f / 32768.f) - mean * mean;
        float scale = g[ch] * rsqrtf(var + 1e-5f);
        stats[ch] = scale;
        stats[64 + ch] = beta[ch] - mean * scale;
    }
}

// ------------- normalize+relu, split o1/o2 -> d_out, float4 ------------------
__global__ void norm2_kernel(const float4* __restrict__ src, const float* __restrict__ stats,
                             float4* __restrict__ out) {
    int idx4 = blockIdx.x * 256 + threadIdx.x;           // over 2*64*4096
    int q = idx4 & 4095;
    int c = (idx4 >> 12) & 63;
    int b = idx4 >> 18;
    float sc = stats[c], sh = stats[64 + c];
    float4 v = src[idx4];
    v.x = fmaxf(fmaf(v.x, sc, sh), 0.f);
    v.y = fmaxf(fmaf(v.y, sc, sh), 0.f);
    v.z = fmaxf(fmaf(v.z, sc, sh), 0.f);
    v.w = fmaxf(fmaf(v.w, sc, sh), 0.f);
    int half = c >> 5, cc = c & 31;
    out[(size_t)half * 262144 + (((size_t)(b * 32 + cc)) << 12) + q] = v;
}

extern "C" void kernel_launch(void* const* d_in, const int* in_sizes, int n_in,
                              void* d_out, int out_size, void* d_ws, size_t ws_size,
                              hipStream_t stream) {
    const float* x1 = (const float*)d_in[0];
    // d_in[1] (x1_) is unused by the reference
    const float* x2 = (const float*)d_in[2];
    const float* Wq = (const float*)d_in[3];
    const float* bq = (const float*)d_in[4];
    const float* Wk = (const float*)d_in[5];
    const float* bk = (const float*)d_in[6];
    const float* Wv = (const float*)d_in[7];
    const float* bv = (const float*)d_in[8];
    const float* W1 = (const float*)d_in[9];
    const float* g1 = (const float*)d_in[10];
    const float* b1 = (const float*)d_in[11];
    const float* W2 = (const float*)d_in[12];
    const float* g2 = (const float*)d_in[13];
    const float* b2 = (const float*)d_in[14];
    float* out = (float*)d_out;
    float* ws = (float*)d_ws;

    // workspace layout (float offsets)
    float* up     = ws;                        // [2][64][HW] fp32
    float* Kf     = ws + 2097152;              // [2][16][HW] fp32
    float* c1out  = ws + 2621440;              // [2][64][HW] fp32
    float* stats  = ws + 4718592;              // 256 (stats1 at +0, stats2 at +128)
    short* hcatN  = (short*)(ws + 4718848);    // [2][HW][128] bf16
    short* h1N    = (short*)(ws + 6816000);    // [2][HW][64]  bf16
    short* Wb1    = (short*)(ws + 7864576);    // 9*4*4*512
    short* Wb2    = (short*)(ws + 7901440);    // 9*2*4*512
    short* Wbk    = (short*)(ws + 7919872);    // 9*2*1*512

    prep_kernel<<<468, 256, 0, stream>>>(W1, W2, Wk, Wb1, Wb2, Wbk);
    upsample_pack_kernel<<<512, 256, 0, stream>>>(x1, up, hcatN);

    // Kf = relu(conv 64->16) on up channels (NHWC ch 64..127)
    convmfma_kernel<128, 64, 64, 16, 1, 1, 1, true><<<512, 256, 0, stream>>>(
        hcatN, Wbk, bk, Kf);

    gate_kernel<<<512, 256, 0, stream>>>(up, Kf, x2, Wq, bq, Wv, bv, hcatN);

    // conv1: 128 -> 64
    convmfma_kernel<128, 0, 128, 64, 2, 2, 2, false><<<512, 256, 0, stream>>>(
        hcatN, Wb1, nullptr, c1out);
    bnstats_kernel<<<64, 256, 0, stream>>>(c1out, g1, b1, stats);
    packN_kernel<<<512, 256, 0, stream>>>(c1out, stats, h1N, 32);

    // conv2: 64 -> 64
    convmfma_kernel<64, 0, 64, 64, 2, 2, 2, false><<<512, 256, 0, stream>>>(
        h1N, Wb2, nullptr, c1out);
    bnstats_kernel<<<64, 256, 0, stream>>>(c1out, g2, b2, stats + 128);
    norm2_kernel<<<2048, 256, 0, stream>>>((const float4*)c1out, stats + 128, (float4*)out);
}

// Round 6
// 116.245 us; speedup vs baseline: 4.7629x; 1.0360x over previous
//
#include <hip/hip_runtime.h>

#define HW 16384      // 128*128

typedef __attribute__((ext_vector_type(8))) short short8v;
typedef __attribute__((ext_vector_type(4))) float f32x4;

__device__ inline short bf16rne(float x) {
    unsigned u = __float_as_uint(x);
    unsigned r = (u + 0x7fffu + ((u >> 16) & 1u)) >> 16;
    return (short)r;
}

// ---------------- fused weight prep: OIHW fp32 -> MFMA B-frag bf16 -----------
// Wb[tap][chunk][octile][lane 64][j 8]; value = W[o][c][tap],
// o = octile*16 + (lane&15), c = chunk*32 + (lane>>4)*8 + j.
__global__ void prep_kernel(const float* __restrict__ W1, const float* __restrict__ W2,
                            const float* __restrict__ Wk,
                            short* __restrict__ Wb1, short* __restrict__ Wb2,
                            short* __restrict__ Wbk) {
    int bid = blockIdx.x;
    const float* W; short* Wb; int CIN, COUT, idx;
    if (bid < 288)      { W = W1; Wb = Wb1; CIN = 128; COUT = 64; idx = bid * 256 + threadIdx.x; }
    else if (bid < 432) { W = W2; Wb = Wb2; CIN = 64;  COUT = 64; idx = (bid - 288) * 256 + threadIdx.x; }
    else                { W = Wk; Wb = Wbk; CIN = 64;  COUT = 16; idx = (bid - 432) * 256 + threadIdx.x; }
    int NOCT = COUT >> 4, NCH = CIN >> 5;
    int total = 9 * NCH * NOCT * 512;
    if (idx >= total) return;
    int j = idx & 7, l = (idx >> 3) & 63;
    int rest = idx >> 9;
    int oct = rest % NOCT; rest /= NOCT;
    int ch = rest % NCH;
    int tap = rest / NCH;
    int o = oct * 16 + (l & 15);
    int c = ch * 32 + (l >> 4) * 8 + j;
    Wb[idx] = bf16rne(W[((size_t)o * CIN + c) * 9 + tap]);
}

// ------- upsample (bilinear 2x align-corners) + write fp32 NCHW + pack NHWC --
__global__ __launch_bounds__(256) void upsample_pack_kernel(
    const float* __restrict__ x1, float* __restrict__ up, short* __restrict__ hcatN)
{
    __shared__ int lds[32 * 65];
    int bid = blockIdx.x;
    const int xh = bid & 1;
    const int oy = (bid >> 1) & 127;
    const int b = bid >> 8;
    const int t = threadIdx.x;
    {
        const int cw = t >> 3, pg = t & 7;
        float fy = (float)(oy * 63) / 127.f;
        int y0 = (int)fy; float wy = fy - (float)y0; int y1 = min(y0 + 1, 63);
        #pragma unroll
        for (int h = 0; h < 2; h++) {
            int c = cw * 2 + h;
            const float* sp = x1 + ((size_t)(b * 64 + c) << 12);
            float vals[8];
            #pragma unroll
            for (int i = 0; i < 8; i++) {
                int ox = xh * 64 + pg * 8 + i;
                float fx = (float)(ox * 63) / 127.f;
                int xx0 = (int)fx; float wx = fx - (float)xx0; int xx1 = min(xx0 + 1, 63);
                float v00 = sp[(y0 << 6) + xx0], v01 = sp[(y0 << 6) + xx1];
                float v10 = sp[(y1 << 6) + xx0], v11 = sp[(y1 << 6) + xx1];
                float top = v00 * (1.f - wx) + v01 * wx;
                float bot = v10 * (1.f - wx) + v11 * wx;
                vals[i] = top * (1.f - wy) + bot * wy;
            }
            float* dp = up + ((size_t)(b * 64 + c) << 14) + (oy << 7) + xh * 64 + pg * 8;
            #pragma unroll
            for (int i = 0; i < 8; i++) dp[i] = vals[i];
            #pragma unroll
            for (int i = 0; i < 8; i++) {
                unsigned wv = (unsigned)(unsigned short)bf16rne(vals[i]);
                if (h == 0) lds[cw * 65 + pg * 8 + i] = (int)wv;
                else        lds[cw * 65 + pg * 8 + i] |= (int)(wv << 16);
            }
        }
    }
    __syncthreads();
    {
        const int px = t >> 2, cq = t & 3;
        int wd[8];
        #pragma unroll
        for (int i = 0; i < 8; i++) wd[i] = lds[(cq * 8 + i) * 65 + px];
        int pixel = (oy << 7) + xh * 64 + px;
        int* dp = (int*)hcatN + (size_t)b * (HW * 64) + (size_t)pixel * 64 + 32 + cq * 8;
        *(int4*)dp = make_int4(wd[0], wd[1], wd[2], wd[3]);
        *(int4*)(dp + 4) = make_int4(wd[4], wd[5], wd[6], wd[7]);
    }
}

// ---------- NCHW fp32 (64ch) -> NHWC bf16 with BN(scale,shift)+relu ----------
__global__ __launch_bounds__(256) void packN_kernel(
    const float* __restrict__ src, const float* __restrict__ stats,
    short* __restrict__ dstN, int PSW)
{
    __shared__ int lds[32 * 65];
    int bid = blockIdx.x;
    const int pxt = bid & 255;
    const int b = bid >> 8;
    const int t = threadIdx.x;
    {
        const int cw = t >> 3, pg = t & 7;
        #pragma unroll
        for (int h = 0; h < 2; h++) {
            int c = cw * 2 + h;
            const float* sp = src + ((size_t)(b * 64 + c) << 14) + pxt * 64 + pg * 8;
            float sc = stats[c], sh = stats[64 + c];
            float4 v0 = *(const float4*)sp;
            float4 v1 = *(const float4*)(sp + 4);
            float vals[8] = {v0.x, v0.y, v0.z, v0.w, v1.x, v1.y, v1.z, v1.w};
            #pragma unroll
            for (int i = 0; i < 8; i++) {
                float v = fmaxf(fmaf(vals[i], sc, sh), 0.f);
                unsigned wv = (unsigned)(unsigned short)bf16rne(v);
                if (h == 0) lds[cw * 65 + pg * 8 + i] = (int)wv;
                else        lds[cw * 65 + pg * 8 + i] |= (int)(wv << 16);
            }
        }
    }
    __syncthreads();
    {
        const int px = t >> 2, cq = t & 3;
        int wd[8];
        #pragma unroll
        for (int i = 0; i < 8; i++) wd[i] = lds[(cq * 8 + i) * 65 + px];
        int pixel = pxt * 64 + px;
        int* dp = (int*)dstN + (size_t)b * HW * (size_t)PSW + (size_t)pixel * PSW + cq * 8;
        *(int4*)dp = make_int4(wd[0], wd[1], wd[2], wd[3]);
        *(int4*)(dp + 4) = make_int4(wd[4], wd[5], wd[6], wd[7]);
    }
}

// ---------------- MFMA implicit-GEMM 3x3 conv, NHWC bf16 in, NCHW fp32 out ---
// wave = (MB*16) px x (OPW*16) oc; block = 4 waves (NWN split oc, NWM=4/NWN split x).
template<int PSTR, int COFF, int CIN, int COUT, int NWN, int OPW, int MB, bool BIASRELU>
__global__ __launch_bounds__(256) void convmfma_kernel(
    const short* __restrict__ actN, const short* __restrict__ Wb,
    const float* __restrict__ bias, float* __restrict__ dst)
{
    constexpr int NCH = CIN / 32, NOCT = COUT / 16, NWM = 4 / NWN;
    constexpr int EXT = NWM * MB * 16;
    constexpr int SEG = 128 / EXT;
    const int t = threadIdx.x;
    const int w = t >> 6, l = t & 63;
    const int wn = w % NWN, wm = w / NWN;
    int bid = blockIdx.x;
    const int xseg = bid % SEG; bid /= SEG;
    const int y = bid & 127;
    const int b = bid >> 7;
    const int lx = l & 15, kg = l >> 4;

    const short* abase = actN + (size_t)b * HW * PSTR + COFF + kg * 8;
    int pxo[MB][3]; bool pxv[MB][3];
    #pragma unroll
    for (int m = 0; m < MB; m++) {
        int x = xseg * EXT + wm * (MB * 16) + m * 16 + lx;
        #pragma unroll
        for (int d = 0; d < 3; d++) {
            int xs = x + d - 1;
            pxv[m][d] = ((unsigned)xs < 128u);
            int xc = xs < 0 ? 0 : (xs > 127 ? 127 : xs);
            pxo[m][d] = xc * PSTR;
        }
    }
    const short* wbase = Wb + (size_t)(wn * OPW) * 512 + (size_t)l * 8;

    f32x4 acc[MB][OPW];
    #pragma unroll
    for (int m = 0; m < MB; m++)
        #pragma unroll
        for (int p = 0; p < OPW; p++) acc[m][p] = (f32x4)(0.f);

    #pragma unroll
    for (int tap = 0; tap < 9; tap++) {
        const int dxi = tap % 3;
        const int ys = y + tap / 3 - 1;
        if ((unsigned)ys < 128u) {
            const short* arow = abase + (size_t)ys * 128 * PSTR;
            #pragma unroll
            for (int ch = 0; ch < NCH; ch++) {
                short8v a[MB];
                #pragma unroll
                for (int m = 0; m < MB; m++) {
                    a[m] = *(const short8v*)(arow + pxo[m][dxi] + ch * 32);
                    if (!pxv[m][dxi]) a[m] = (short8v)(short)0;
                }
                #pragma unroll
                for (int p = 0; p < OPW; p++) {
                    short8v bf = *(const short8v*)(wbase +
                        (size_t)((tap * NCH + ch) * NOCT + p) * 512);
                    #pragma unroll
                    for (int m = 0; m < MB; m++)
                        acc[m][p] = __builtin_amdgcn_mfma_f32_16x16x32_bf16(a[m], bf, acc[m][p], 0, 0, 0);
                }
            }
        }
    }

    #pragma unroll
    for (int m = 0; m < MB; m++) {
        const int ox = xseg * EXT + wm * (MB * 16) + m * 16 + kg * 4;
        #pragma unroll
        for (int p = 0; p < OPW; p++) {
            const int oc = (wn * OPW + p) * 16 + lx;
            f32x4 v = acc[m][p];
            if (BIASRELU) {
                float bb = bias[oc];
                #pragma unroll
                for (int r = 0; r < 4; r++) v[r] = fmaxf(v[r] + bb, 0.f);
            }
            *(f32x4*)(dst + (((size_t)(b * COUT + oc)) << 14) + (y << 7) + ox) = v;
        }
    }
}

// ------------- fused qconv + softmax gate + NHWC bf16 pack -------------------
// block = (b, y, xh): 64 px x 64 ch; lane = consecutive px (coalesced loads);
// wave cg handles channels [cg*16, cg*16+16).
__global__ __launch_bounds__(256) void gate_kernel(
    const float* __restrict__ up, const float* __restrict__ Kf,
    const float* __restrict__ x2,
    const float* __restrict__ Wq, const float* __restrict__ bq,
    const float* __restrict__ Wv, const float* __restrict__ bv,
    short* __restrict__ hcatN)
{
    __shared__ float kfs[16 * 65];
    __shared__ int tr[32 * 65];
    int bid = blockIdx.x;
    const int xh = bid & 1;
    const int y = (bid >> 1) & 127;
    const int b = bid >> 8;
    const int t = threadIdx.x;

    {   // stage Kf tile [16 k][64 px] (coalesced float4)
        int k = t >> 4, pq = (t & 15) * 4;
        const float* sp = Kf + ((size_t)(b * 16 + k) << 14) + (y << 7) + xh * 64 + pq;
        float4 v = *(const float4*)sp;
        float* d = kfs + k * 65 + pq;
        d[0] = v.x; d[1] = v.y; d[2] = v.z; d[3] = v.w;
    }
    __syncthreads();

    const int cg = t >> 6, lane = t & 63;
    const int x = xh * 64 + lane;

    float kv[16];
    #pragma unroll
    for (int k = 0; k < 16; k++) kv[k] = kfs[k * 65 + lane];
    float kvmax = kv[0];
    #pragma unroll
    for (int k = 1; k < 16; k++) kvmax = fmaxf(kvmax, kv[k]);

    float wvv[16], bvv[16];
    #pragma unroll
    for (int k = 0; k < 16; k++) { wvv[k] = Wv[k]; bvv[k] = bv[k]; }

    const bool xm_ok = (x >= 1), xp_ok = (x <= 126);

    int gpack[8];
    #pragma unroll
    for (int j = 0; j < 8; j++) {
        gpack[j] = 0;
        #pragma unroll
        for (int h = 0; h < 2; h++) {
            const int c = cg * 16 + j * 2 + h;
            const float* upc = up + ((size_t)(b * 64 + c) << 14);
            const float* wq = Wq + c * 9;                 // wave-uniform
            float q = bq[c];
            #pragma unroll
            for (int r = 0; r < 3; r++) {
                int yy = y + r - 1;
                bool yv = ((unsigned)yy < 128u);
                const float* rp = upc + (yy << 7);
                float vm = (yv && xm_ok) ? rp[x - 1] : 0.f;
                float vc = yv            ? rp[x]     : 0.f;
                float vp = (yv && xp_ok) ? rp[x + 1] : 0.f;
                q = fmaf(vm, wq[r * 3 + 0], q);
                q = fmaf(vc, wq[r * 3 + 1], q);
                q = fmaf(vp, wq[r * 3 + 2], q);
            }
            q = fmaxf(q, 0.f);
            float xvv = x2[((size_t)(b * 64 + c) << 14) + (y << 7) + x];
            float mx = q * kvmax;                         // q,kv >= 0 => exact max
            float den = 0.f, num = 0.f;
            #pragma unroll
            for (int k = 0; k < 16; k++) {
                float e = __expf(fmaf(q, kv[k], -mx));
                den += e;
                float V = fmaxf(fmaf(xvv, wvv[k], bvv[k]), 0.f);
                num = fmaf(e, V, num);
            }
            unsigned u = (unsigned)(unsigned short)bf16rne(num / den);
            gpack[j] |= (int)(u << (h * 16));
        }
    }
    #pragma unroll
    for (int j = 0; j < 8; j++) tr[(cg * 8 + j) * 65 + lane] = gpack[j];
    __syncthreads();
    {
        const int px = t >> 2, cq = t & 3;
        int wd[8];
        #pragma unroll
        for (int i = 0; i < 8; i++) wd[i] = tr[(cq * 8 + i) * 65 + px];
        int pixel = (y << 7) + xh * 64 + px;
        int* dp = (int*)hcatN + (size_t)b * (HW * 64) + (size_t)pixel * 64 + cq * 8;
        *(int4*)dp = make_int4(wd[0], wd[1], wd[2], wd[3]);
        *(int4*)(dp + 4) = make_int4(wd[4], wd[5], wd[6], wd[7]);
    }
}

// ------------- BN stats: one block per channel; stats = {scale[64],shift[64]}
__global__ void bnstats_kernel(const float* __restrict__ src, const float* __restrict__ g,
                               const float* __restrict__ beta, float* __restrict__ stats) {
    int ch = blockIdx.x;
    float s = 0.f, sq = 0.f;
    for (int b = 0; b < 2; b++) {
        const float4* p = reinterpret_cast<const float4*>(src + ((size_t)(b * 64 + ch) << 14));
        for (int i = threadIdx.x; i < 4096; i += 256) {
            float4 v = p[i];
            s += v.x + v.y + v.z + v.w;
            sq = fmaf(v.x, v.x, fmaf(v.y, v.y, fmaf(v.z, v.z, fmaf(v.w, v.w, sq))));
        }
    }
    __shared__ float sh[512];
    sh[threadIdx.x] = s;
    sh[256 + threadIdx.x] = sq;
    __syncthreads();
    for (int off = 128; off > 0; off >>= 1) {
        if ((int)threadIdx.x < off) {
            sh[threadIdx.x] += sh[threadIdx.x + off];
            sh[256 + threadIdx.x] += sh[256 + threadIdx.x + off];
        }
        __syncthreads();
    }
    if (threadIdx.x == 0) {
        float mean = sh[0] * (1.f / 32768.f);
        float var = sh[256] * (1.f / 32768.f) - mean * mean;
        float scale = g[ch] * rsqrtf(var + 1e-5f);
        stats[ch] = scale;
        stats[64 + ch] = beta[ch] - mean * scale;
    }
}

// ------------- normalize+relu, split o1/o2 -> d_out, float4 ------------------
__global__ void norm2_kernel(const float4* __restrict__ src, const float* __restrict__ stats,
                             float4* __restrict__ out) {
    int idx4 = blockIdx.x * 256 + threadIdx.x;           // over 2*64*4096
    int q = idx4 & 4095;
    int c = (idx4 >> 12) & 63;
    int b = idx4 >> 18;
    float sc = stats[c], sh = stats[64 + c];
    float4 v = src[idx4];
    v.x = fmaxf(fmaf(v.x, sc, sh), 0.f);
    v.y = fmaxf(fmaf(v.y, sc, sh), 0.f);
    v.z = fmaxf(fmaf(v.z, sc, sh), 0.f);
    v.w = fmaxf(fmaf(v.w, sc, sh), 0.f);
    int half = c >> 5, cc = c & 31;
    out[(size_t)half * 262144 + (((size_t)(b * 32 + cc)) << 12) + q] = v;
}

extern "C" void kernel_launch(void* const* d_in, const int* in_sizes, int n_in,
                              void* d_out, int out_size, void* d_ws, size_t ws_size,
                              hipStream_t stream) {
    const float* x1 = (const float*)d_in[0];
    // d_in[1] (x1_) is unused by the reference
    const float* x2 = (const float*)d_in[2];
    const float* Wq = (const float*)d_in[3];
    const float* bq = (const float*)d_in[4];
    const float* Wk = (const float*)d_in[5];
    const float* bk = (const float*)d_in[6];
    const float* Wv = (const float*)d_in[7];
    const float* bv = (const float*)d_in[8];
    const float* W1 = (const float*)d_in[9];
    const float* g1 = (const float*)d_in[10];
    const float* b1 = (const float*)d_in[11];
    const float* W2 = (const float*)d_in[12];
    const float* g2 = (const float*)d_in[13];
    const float* b2 = (const float*)d_in[14];
    float* out = (float*)d_out;
    float* ws = (float*)d_ws;

    // workspace layout (float offsets)
    float* up     = ws;                        // [2][64][HW] fp32
    float* Kf     = ws + 2097152;              // [2][16][HW] fp32
    float* c1out  = ws + 2621440;              // [2][64][HW] fp32
    float* stats  = ws + 4718592;              // 256 (stats1 at +0, stats2 at +128)
    short* hcatN  = (short*)(ws + 4718848);    // [2][HW][128] bf16
    short* h1N    = (short*)(ws + 6816000);    // [2][HW][64]  bf16
    short* Wb1    = (short*)(ws + 7864576);    // 9*4*4*512
    short* Wb2    = (short*)(ws + 7901440);    // 9*2*4*512
    short* Wbk    = (short*)(ws + 7919872);    // 9*2*1*512

    prep_kernel<<<468, 256, 0, stream>>>(W1, W2, Wk, Wb1, Wb2, Wbk);
    upsample_pack_kernel<<<512, 256, 0, stream>>>(x1, up, hcatN);

    // Kf = relu(conv 64->16) on up channels (NHWC ch 64..127)
    convmfma_kernel<128, 64, 64, 16, 1, 1, 1, true><<<512, 256, 0, stream>>>(
        hcatN, Wbk, bk, Kf);

    gate_kernel<<<512, 256, 0, stream>>>(up, Kf, x2, Wq, bq, Wv, bv, hcatN);

    // conv1: 128 -> 64
    convmfma_kernel<128, 0, 128, 64, 2, 2, 2, false><<<512, 256, 0, stream>>>(
        hcatN, Wb1, nullptr, c1out);
    bnstats_kernel<<<64, 256, 0, stream>>>(c1out, g1, b1, stats);
    packN_kernel<<<512, 256, 0, stream>>>(c1out, stats, h1N, 32);

    // conv2: 64 -> 64
    convmfma_kernel<64, 0, 64, 64, 2, 2, 2, false><<<512, 256, 0, stream>>>(
        h1N, Wb2, nullptr, c1out);
    bnstats_kernel<<<64, 256, 0, stream>>>(c1out, g2, b2, stats + 128);
    norm2_kernel<<<2048, 256, 0, stream>>>((const float4*)c1out, stats + 128, (float4*)out);
}

// Round 7
// 114.783 us; speedup vs baseline: 4.8235x; 1.0127x over previous
//
#include <hip/hip_runtime.h>

#define HW 16384      // 128*128

typedef __attribute__((ext_vector_type(8))) short short8v;
typedef __attribute__((ext_vector_type(4))) float f32x4;

__device__ inline short bf16rne(float x) {
    unsigned u = __float_as_uint(x);
    unsigned r = (u + 0x7fffu + ((u >> 16) & 1u)) >> 16;
    return (short)r;
}

// ---------------- fused weight prep: OIHW fp32 -> MFMA B-frag bf16 -----------
__global__ void prep_kernel(const float* __restrict__ W1, const float* __restrict__ W2,
                            const float* __restrict__ Wk,
                            short* __restrict__ Wb1, short* __restrict__ Wb2,
                            short* __restrict__ Wbk) {
    int bid = blockIdx.x;
    const float* W; short* Wb; int CIN, COUT, idx;
    if (bid < 288)      { W = W1; Wb = Wb1; CIN = 128; COUT = 64; idx = bid * 256 + threadIdx.x; }
    else if (bid < 432) { W = W2; Wb = Wb2; CIN = 64;  COUT = 64; idx = (bid - 288) * 256 + threadIdx.x; }
    else                { W = Wk; Wb = Wbk; CIN = 64;  COUT = 16; idx = (bid - 432) * 256 + threadIdx.x; }
    int NOCT = COUT >> 4, NCH = CIN >> 5;
    int total = 9 * NCH * NOCT * 512;
    if (idx >= total) return;
    int j = idx & 7, l = (idx >> 3) & 63;
    int rest = idx >> 9;
    int oct = rest % NOCT; rest /= NOCT;
    int ch = rest % NCH;
    int tap = rest / NCH;
    int o = oct * 16 + (l & 15);
    int c = ch * 32 + (l >> 4) * 8 + j;
    Wb[idx] = bf16rne(W[((size_t)o * CIN + c) * 9 + tap]);
}

// ------- upsample (bilinear 2x align-corners) + write fp32 NCHW + pack NHWC --
__global__ __launch_bounds__(256) void upsample_pack_kernel(
    const float* __restrict__ x1, float* __restrict__ up, short* __restrict__ hcatN)
{
    __shared__ int lds[32 * 65];
    int bid = blockIdx.x;
    const int xh = bid & 1;
    const int oy = (bid >> 1) & 127;
    const int b = bid >> 8;
    const int t = threadIdx.x;
    {
        const int cw = t >> 3, pg = t & 7;
        float fy = (float)(oy * 63) / 127.f;
        int y0 = (int)fy; float wy = fy - (float)y0; int y1 = min(y0 + 1, 63);
        #pragma unroll
        for (int h = 0; h < 2; h++) {
            int c = cw * 2 + h;
            const float* sp = x1 + ((size_t)(b * 64 + c) << 12);
            float vals[8];
            #pragma unroll
            for (int i = 0; i < 8; i++) {
                int ox = xh * 64 + pg * 8 + i;
                float fx = (float)(ox * 63) / 127.f;
                int xx0 = (int)fx; float wx = fx - (float)xx0; int xx1 = min(xx0 + 1, 63);
                float v00 = sp[(y0 << 6) + xx0], v01 = sp[(y0 << 6) + xx1];
                float v10 = sp[(y1 << 6) + xx0], v11 = sp[(y1 << 6) + xx1];
                float top = v00 * (1.f - wx) + v01 * wx;
                float bot = v10 * (1.f - wx) + v11 * wx;
                vals[i] = top * (1.f - wy) + bot * wy;
            }
            float* dp = up + ((size_t)(b * 64 + c) << 14) + (oy << 7) + xh * 64 + pg * 8;
            #pragma unroll
            for (int i = 0; i < 8; i++) dp[i] = vals[i];
            #pragma unroll
            for (int i = 0; i < 8; i++) {
                unsigned wv = (unsigned)(unsigned short)bf16rne(vals[i]);
                if (h == 0) lds[cw * 65 + pg * 8 + i] = (int)wv;
                else        lds[cw * 65 + pg * 8 + i] |= (int)(wv << 16);
            }
        }
    }
    __syncthreads();
    {
        const int px = t >> 2, cq = t & 3;
        int wd[8];
        #pragma unroll
        for (int i = 0; i < 8; i++) wd[i] = lds[(cq * 8 + i) * 65 + px];
        int pixel = (oy << 7) + xh * 64 + px;
        int* dp = (int*)hcatN + (size_t)b * (HW * 64) + (size_t)pixel * 64 + 32 + cq * 8;
        *(int4*)dp = make_int4(wd[0], wd[1], wd[2], wd[3]);
        *(int4*)(dp + 4) = make_int4(wd[4], wd[5], wd[6], wd[7]);
    }
}

// ---------- NCHW fp32 (64ch) -> NHWC bf16 with BN(scale,shift)+relu ----------
__global__ __launch_bounds__(256) void packN_kernel(
    const float* __restrict__ src, const float* __restrict__ stats,
    short* __restrict__ dstN, int PSW)
{
    __shared__ int lds[32 * 65];
    int bid = blockIdx.x;
    const int pxt = bid & 255;
    const int b = bid >> 8;
    const int t = threadIdx.x;
    {
        const int cw = t >> 3, pg = t & 7;
        #pragma unroll
        for (int h = 0; h < 2; h++) {
            int c = cw * 2 + h;
            const float* sp = src + ((size_t)(b * 64 + c) << 14) + pxt * 64 + pg * 8;
            float sc = stats[c], sh = stats[64 + c];
            float4 v0 = *(const float4*)sp;
            float4 v1 = *(const float4*)(sp + 4);
            float vals[8] = {v0.x, v0.y, v0.z, v0.w, v1.x, v1.y, v1.z, v1.w};
            #pragma unroll
            for (int i = 0; i < 8; i++) {
                float v = fmaxf(fmaf(vals[i], sc, sh), 0.f);
                unsigned wv = (unsigned)(unsigned short)bf16rne(v);
                if (h == 0) lds[cw * 65 + pg * 8 + i] = (int)wv;
                else        lds[cw * 65 + pg * 8 + i] |= (int)(wv << 16);
            }
        }
    }
    __syncthreads();
    {
        const int px = t >> 2, cq = t & 3;
        int wd[8];
        #pragma unroll
        for (int i = 0; i < 8; i++) wd[i] = lds[(cq * 8 + i) * 65 + px];
        int pixel = pxt * 64 + px;
        int* dp = (int*)dstN + (size_t)b * HW * (size_t)PSW + (size_t)pixel * PSW + cq * 8;
        *(int4*)dp = make_int4(wd[0], wd[1], wd[2], wd[3]);
        *(int4*)(dp + 4) = make_int4(wd[4], wd[5], wd[6], wd[7]);
    }
}

// ---------------- MFMA implicit-GEMM 3x3 conv, NHWC bf16 in, NCHW fp32 out ---
template<int PSTR, int COFF, int CIN, int COUT, int NWN, int OPW, int MB, bool BIASRELU>
__global__ __launch_bounds__(256) void convmfma_kernel(
    const short* __restrict__ actN, const short* __restrict__ Wb,
    const float* __restrict__ bias, float* __restrict__ dst)
{
    constexpr int NCH = CIN / 32, NOCT = COUT / 16, NWM = 4 / NWN;
    constexpr int EXT = NWM * MB * 16;
    constexpr int SEG = 128 / EXT;
    const int t = threadIdx.x;
    const int w = t >> 6, l = t & 63;
    const int wn = w % NWN, wm = w / NWN;
    int bid = blockIdx.x;
    const int xseg = bid % SEG; bid /= SEG;
    const int y = bid & 127;
    const int b = bid >> 7;
    const int lx = l & 15, kg = l >> 4;

    const short* abase = actN + (size_t)b * HW * PSTR + COFF + kg * 8;
    int pxo[MB][3]; bool pxv[MB][3];
    #pragma unroll
    for (int m = 0; m < MB; m++) {
        int x = xseg * EXT + wm * (MB * 16) + m * 16 + lx;
        #pragma unroll
        for (int d = 0; d < 3; d++) {
            int xs = x + d - 1;
            pxv[m][d] = ((unsigned)xs < 128u);
            int xc = xs < 0 ? 0 : (xs > 127 ? 127 : xs);
            pxo[m][d] = xc * PSTR;
        }
    }
    const short* wbase = Wb + (size_t)(wn * OPW) * 512 + (size_t)l * 8;

    f32x4 acc[MB][OPW];
    #pragma unroll
    for (int m = 0; m < MB; m++)
        #pragma unroll
        for (int p = 0; p < OPW; p++) acc[m][p] = (f32x4)(0.f);

    #pragma unroll
    for (int tap = 0; tap < 9; tap++) {
        const int dxi = tap % 3;
        const int ys = y + tap / 3 - 1;
        if ((unsigned)ys < 128u) {
            const short* arow = abase + (size_t)ys * 128 * PSTR;
            #pragma unroll
            for (int ch = 0; ch < NCH; ch++) {
                short8v a[MB];
                #pragma unroll
                for (int m = 0; m < MB; m++) {
                    a[m] = *(const short8v*)(arow + pxo[m][dxi] + ch * 32);
                    if (!pxv[m][dxi]) a[m] = (short8v)(short)0;
                }
                #pragma unroll
                for (int p = 0; p < OPW; p++) {
                    short8v bf = *(const short8v*)(wbase +
                        (size_t)((tap * NCH + ch) * NOCT + p) * 512);
                    #pragma unroll
                    for (int m = 0; m < MB; m++)
                        acc[m][p] = __builtin_amdgcn_mfma_f32_16x16x32_bf16(a[m], bf, acc[m][p], 0, 0, 0);
                }
            }
        }
    }

    #pragma unroll
    for (int m = 0; m < MB; m++) {
        const int ox = xseg * EXT + wm * (MB * 16) + m * 16 + kg * 4;
        #pragma unroll
        for (int p = 0; p < OPW; p++) {
            const int oc = (wn * OPW + p) * 16 + lx;
            f32x4 v = acc[m][p];
            if (BIASRELU) {
                float bb = bias[oc];
                #pragma unroll
                for (int r = 0; r < 4; r++) v[r] = fmaxf(v[r] + bb, 0.f);
            }
            *(f32x4*)(dst + (((size_t)(b * COUT + oc)) << 14) + (y << 7) + ox) = v;
        }
    }
}

// ------------- depthwise 3x3 + relu (streaming, coalesced): up -> Qb ---------
__global__ void qconv_kernel(const float* __restrict__ up, const float* __restrict__ Wq,
                             const float* __restrict__ bq, float* __restrict__ Qb) {
    int idx = blockIdx.x * 256 + threadIdx.x;            // over 2*64*HW
    int hw = idx & (HW - 1);
    int bc = idx >> 14;
    int c = bc & 63;
    int y = hw >> 7, x = hw & 127;
    const float* s = up + ((size_t)bc << 14);
    const float* w = Wq + c * 9;                         // wave-uniform -> s_load
    const bool xm = (x >= 1), xp = (x <= 126);
    float acc = bq[c];
    #pragma unroll
    for (int r = 0; r < 3; r++) {
        int yy = y + r - 1;
        bool yv = ((unsigned)yy < 128u);
        const float* rp = s + (yy << 7);
        float vm = (yv && xm) ? rp[x - 1] : 0.f;
        float vc = yv         ? rp[x]     : 0.f;
        float vp = (yv && xp) ? rp[x + 1] : 0.f;
        acc = fmaf(vm, w[r * 3 + 0], acc);
        acc = fmaf(vc, w[r * 3 + 1], acc);
        acc = fmaf(vp, w[r * 3 + 2], acc);
    }
    Qb[idx] = fmaxf(acc, 0.f);
}

// ------------- softmax gate + NHWC bf16 pack ---------------------------------
// block = (b, y, xh, ch32): 64 px (lane) x 32 ch; wave cg handles 8 channels;
// thread = 8 outputs, 2 loads each (Q, x2). grid = 1024.
__global__ __launch_bounds__(256) void gate_kernel(
    const float* __restrict__ Qb, const float* __restrict__ Kf,
    const float* __restrict__ x2,
    const float* __restrict__ Wv, const float* __restrict__ bv,
    short* __restrict__ hcatN)
{
    __shared__ float kfs[16 * 65];
    __shared__ int tr[16 * 65];
    int bid = blockIdx.x;
    const int ch32 = bid & 1;
    const int xh = (bid >> 1) & 1;
    const int y = (bid >> 2) & 127;
    const int b = bid >> 9;
    const int t = threadIdx.x;

    {   // stage Kf tile [16 k][64 px] (coalesced float4)
        int k = t >> 4, pq = (t & 15) * 4;
        const float* sp = Kf + ((size_t)(b * 16 + k) << 14) + (y << 7) + xh * 64 + pq;
        float4 v = *(const float4*)sp;
        float* d = kfs + k * 65 + pq;
        d[0] = v.x; d[1] = v.y; d[2] = v.z; d[3] = v.w;
    }
    __syncthreads();

    const int cg = t >> 6, lane = t & 63;
    const int x = xh * 64 + lane;

    float kv[16];
    #pragma unroll
    for (int k = 0; k < 16; k++) kv[k] = kfs[k * 65 + lane];
    float kvmax = kv[0];
    #pragma unroll
    for (int k = 1; k < 16; k++) kvmax = fmaxf(kvmax, kv[k]);

    float wvv[16], bvv[16];
    #pragma unroll
    for (int k = 0; k < 16; k++) { wvv[k] = Wv[k]; bvv[k] = bv[k]; }

    // issue all 16 loads up-front (independent, coalesced)
    float qv[4][2], xvv[4][2];
    #pragma unroll
    for (int j = 0; j < 4; j++)
        #pragma unroll
        for (int h = 0; h < 2; h++) {
            const int c = ch32 * 32 + cg * 8 + j * 2 + h;
            size_t off = ((size_t)(b * 64 + c) << 14) + (y << 7) + x;
            qv[j][h] = Qb[off];
            xvv[j][h] = x2[off];
        }

    #pragma unroll
    for (int j = 0; j < 4; j++) {
        int gpack = 0;
        #pragma unroll
        for (int h = 0; h < 2; h++) {
            float q = qv[j][h];
            float mx = q * kvmax;                         // q,kv >= 0 => exact max
            float den = 0.f, num = 0.f;
            #pragma unroll
            for (int k = 0; k < 16; k++) {
                float e = __expf(fmaf(q, kv[k], -mx));
                den += e;
                float V = fmaxf(fmaf(xvv[j][h], wvv[k], bvv[k]), 0.f);
                num = fmaf(e, V, num);
            }
            unsigned u = (unsigned)(unsigned short)bf16rne(num / den);
            gpack |= (int)(u << (h * 16));
        }
        tr[(cg * 4 + j) * 65 + lane] = gpack;
    }
    __syncthreads();
    {
        const int px = t >> 2, cq = t & 3;
        int wd[4];
        #pragma unroll
        for (int i = 0; i < 4; i++) wd[i] = tr[(cq * 4 + i) * 65 + px];
        int pixel = (y << 7) + xh * 64 + px;
        int* dp = (int*)hcatN + (size_t)b * (HW * 64) + (size_t)pixel * 64 + ch32 * 16 + cq * 4;
        *(int4*)dp = make_int4(wd[0], wd[1], wd[2], wd[3]);
    }
}

// ------------- BN stats: one block per channel; stats = {scale[64],shift[64]}
__global__ void bnstats_kernel(const float* __restrict__ src, const float* __restrict__ g,
                               const float* __restrict__ beta, float* __restrict__ stats) {
    int ch = blockIdx.x;
    float s = 0.f, sq = 0.f;
    for (int b = 0; b < 2; b++) {
        const float4* p = reinterpret_cast<const float4*>(src + ((size_t)(b * 64 + ch) << 14));
        for (int i = threadIdx.x; i < 4096; i += 256) {
            float4 v = p[i];
            s += v.x + v.y + v.z + v.w;
            sq = fmaf(v.x, v.x, fmaf(v.y, v.y, fmaf(v.z, v.z, fmaf(v.w, v.w, sq))));
        }
    }
    __shared__ float sh[512];
    sh[threadIdx.x] = s;
    sh[256 + threadIdx.x] = sq;
    __syncthreads();
    for (int off = 128; off > 0; off >>= 1) {
        if ((int)threadIdx.x < off) {
            sh[threadIdx.x] += sh[threadIdx.x + off];
            sh[256 + threadIdx.x] += sh[256 + threadIdx.x + off];
        }
        __syncthreads();
    }
    if (threadIdx.x == 0) {
        float mean = sh[0] * (1.f / 32768.f);
        float var = sh[256] * (1.f / 32768.f) - mean * mean;
        float scale = g[ch] * rsqrtf(var + 1e-5f);
        stats[ch] = scale;
        stats[64 + ch] = beta[ch] - mean * scale;
    }
}

// ------------- normalize+relu, split o1/o2 -> d_out, float4 ------------------
__global__ void norm2_kernel(const float4* __restrict__ src, const float* __restrict__ stats,
                             float4* __restrict__ out) {
    int idx4 = blockIdx.x * 256 + threadIdx.x;           // over 2*64*4096
    int q = idx4 & 4095;
    int c = (idx4 >> 12) & 63;
    int b = idx4 >> 18;
    float sc = stats[c], sh = stats[64 + c];
    float4 v = src[idx4];
    v.x = fmaxf(fmaf(v.x, sc, sh), 0.f);
    v.y = fmaxf(fmaf(v.y, sc, sh), 0.f);
    v.z = fmaxf(fmaf(v.z, sc, sh), 0.f);
    v.w = fmaxf(fmaf(v.w, sc, sh), 0.f);
    int half = c >> 5, cc = c & 31;
    out[(size_t)half * 262144 + (((size_t)(b * 32 + cc)) << 12) + q] = v;
}

extern "C" void kernel_launch(void* const* d_in, const int* in_sizes, int n_in,
                              void* d_out, int out_size, void* d_ws, size_t ws_size,
                              hipStream_t stream) {
    const float* x1 = (const float*)d_in[0];
    // d_in[1] (x1_) is unused by the reference
    const float* x2 = (const float*)d_in[2];
    const float* Wq = (const float*)d_in[3];
    const float* bq = (const float*)d_in[4];
    const float* Wk = (const float*)d_in[5];
    const float* bk = (const float*)d_in[6];
    const float* Wv = (const float*)d_in[7];
    const float* bv = (const float*)d_in[8];
    const float* W1 = (const float*)d_in[9];
    const float* g1 = (const float*)d_in[10];
    const float* b1 = (const float*)d_in[11];
    const float* W2 = (const float*)d_in[12];
    const float* g2 = (const float*)d_in[13];
    const float* b2 = (const float*)d_in[14];
    float* out = (float*)d_out;
    float* ws = (float*)d_ws;

    // workspace layout (float offsets)
    float* up     = ws;                        // [2][64][HW] fp32
    float* Qb     = ws + 2097152;              // [2][64][HW] fp32
    float* Kf     = ws + 4194304;              // [2][16][HW] fp32
    float* c1out  = ws + 4718592;              // [2][64][HW] fp32
    float* stats  = ws + 6815744;              // 256 (stats1 at +0, stats2 at +128)
    short* hcatN  = (short*)(ws + 6816000);    // [2][HW][128] bf16
    short* h1N    = (short*)(ws + 8913152);    // [2][HW][64]  bf16
    short* Wb1    = (short*)(ws + 9961728);    // 9*4*4*512
    short* Wb2    = (short*)(ws + 9998592);    // 9*2*4*512
    short* Wbk    = (short*)(ws + 10017024);   // 9*2*1*512

    prep_kernel<<<468, 256, 0, stream>>>(W1, W2, Wk, Wb1, Wb2, Wbk);
    upsample_pack_kernel<<<512, 256, 0, stream>>>(x1, up, hcatN);

    // Kf = relu(conv 64->16) on up channels (NHWC ch 64..127)
    convmfma_kernel<128, 64, 64, 16, 1, 1, 1, true><<<512, 256, 0, stream>>>(
        hcatN, Wbk, bk, Kf);

    qconv_kernel<<<8192, 256, 0, stream>>>(up, Wq, bq, Qb);
    gate_kernel<<<1024, 256, 0, stream>>>(Qb, Kf, x2, Wv, bv, hcatN);

    // conv1: 128 -> 64
    convmfma_kernel<128, 0, 128, 64, 2, 2, 2, false><<<512, 256, 0, stream>>>(
        hcatN, Wb1, nullptr, c1out);
    bnstats_kernel<<<64, 256, 0, stream>>>(c1out, g1, b1, stats);
    packN_kernel<<<512, 256, 0, stream>>>(c1out, stats, h1N, 32);

    // conv2: 64 -> 64
    convmfma_kernel<64, 0, 64, 64, 2, 2, 2, false><<<512, 256, 0, stream>>>(
        h1N, Wb2, nullptr, c1out);
    bnstats_kernel<<<64, 256, 0, stream>>>(c1out, g2, b2, stats + 128);
    norm2_kernel<<<2048, 256, 0, stream>>>((const float4*)c1out, stats + 128, (float4*)out);
}